// Round 2
// baseline (1960.075 us; speedup 1.0000x reference)
//
#include <hip/hip_runtime.h>
#include <math.h>

// Problem dims
#define TB 16   // batch (tasks)
#define TT 16   // train steps
#define LL 128  // test length
#define XX 256  // x dim
#define HH 512  // hidden
#define YY 256  // y dim

#define NWG 128 // workgroups in persistent inner-loop kernel (co-resident: 128 << 256 CUs)

__device__ __forceinline__ float wred(float v) {
    v += __shfl_xor(v, 32);
    v += __shfl_xor(v, 16);
    v += __shfl_xor(v, 8);
    v += __shfl_xor(v, 4);
    v += __shfl_xor(v, 2);
    v += __shfl_xor(v, 1);
    return v;
}

// Grid barrier: one counter per barrier instance, zeroed by hipMemsetAsync
// before the launch. All NWG WGs are co-resident (128 WGs of 256 thr on 256
// CUs), so spinning is safe.
__device__ __forceinline__ void gbar(unsigned* cnt, int idx) {
    __syncthreads();
    if (threadIdx.x == 0) {
        __threadfence();               // release all prior global writes
        atomicAdd(&cnt[idx], 1u);      // device-scope by default
        while (__hip_atomic_load(&cnt[idx], __ATOMIC_ACQUIRE,
                                 __HIP_MEMORY_SCOPE_AGENT) < NWG)
            __builtin_amdgcn_s_sleep(1);
    }
    __syncthreads();                   // thread0's acquire invalidated this CU's L1
}

// ---------------------------------------------------------------------------
// Z1 = train_x @ W1^T + b1 as a tiled GEMM  [256 m] x [512 n] x [256 k]
// epilogue: H1[b][0] = relu(Z1[b][0]).  grid: 64 WGs of 256.
// ---------------------------------------------------------------------------
__global__ __launch_bounds__(256) void k_z1(
    const float* __restrict__ W1, const float* __restrict__ b1,
    const float* __restrict__ tx, float* __restrict__ Z1base,
    float* __restrict__ H1)
{
    const int nc = blockIdx.x & 7, mc = blockIdx.x >> 3;
    const int tid = threadIdx.x;
    const int tn = tid & 31, tl = tid >> 5;
    __shared__ float lw[64][65];
    __shared__ float lx[32][65];
    float acc[2][4] = {};
    for (int kc = 0; kc < XX; kc += 64) {
        __syncthreads();
        #pragma unroll
        for (int rep = 0; rep < 16; ++rep) {
            const int flat = rep * 256 + tid;
            const int i = flat >> 6, k = flat & 63;
            lw[i][k] = W1[(nc * 64 + i) * XX + kc + k];
        }
        #pragma unroll
        for (int rep = 0; rep < 8; ++rep) {
            const int flat = rep * 256 + tid;
            const int l = flat >> 6, k = flat & 63;
            lx[l][k] = tx[(mc * 32 + l) * XX + kc + k];
        }
        __syncthreads();
        #pragma unroll 4
        for (int k = 0; k < 64; ++k) {
            const float w0 = lw[tn][k], w1 = lw[tn + 32][k];
            const float x0 = lx[tl][k],      x1 = lx[tl + 8][k];
            const float x2 = lx[tl + 16][k], x3 = lx[tl + 24][k];
            acc[0][0] += w0 * x0; acc[0][1] += w0 * x1;
            acc[0][2] += w0 * x2; acc[0][3] += w0 * x3;
            acc[1][0] += w1 * x0; acc[1][1] += w1 * x1;
            acc[1][2] += w1 * x2; acc[1][3] += w1 * x3;
        }
    }
    #pragma unroll
    for (int i = 0; i < 2; ++i) {
        const int n = nc * 64 + tn + i * 32;
        const float bv = b1[n];
        #pragma unroll
        for (int j = 0; j < 4; ++j) {
            const int m = mc * 32 + tl + j * 8;
            const float v = acc[i][j] + bv;
            Z1base[m * HH + n] = v;
            if ((m & 15) == 0) H1[m * HH + n] = fmaxf(v, 0.0f);  // t==0
        }
    }
}

// ---------------------------------------------------------------------------
// Gram: G1[b][s][t] = x_s.x_t + 1 ; also out[2048] = exp(loglr).
// grid: B blocks of 256 (thread = (s,t) pair).
// ---------------------------------------------------------------------------
__global__ __launch_bounds__(256) void k_gram(
    const float* __restrict__ tx, const float* __restrict__ loglr,
    float* __restrict__ G1, float* __restrict__ out)
{
    const int b = blockIdx.x;
    const int tid = threadIdx.x;
    __shared__ float sx[TT][XX + 1];
    #pragma unroll
    for (int rep = 0; rep < 16; ++rep) {
        const int flat = rep * 256 + tid;
        const int s = flat >> 8, k = flat & 255;
        sx[s][k] = tx[(b * TT + s) * XX + k];
    }
    __syncthreads();
    if (b == 0 && tid == 0) out[2048] = expf(loglr[0]);
    const int s = tid >> 4, t = tid & 15;
    float a = 0.0f;
    #pragma unroll 8
    for (int k = 0; k < XX; ++k) a += sx[s][k] * sx[t][k];
    G1[(b * TT + s) * TT + t] = a + 1.0f;
}

// ---------------------------------------------------------------------------
// Stage device functions for the persistent inner-loop kernel.
// WG = (b, hc): example b, row-chunk hc (8 chunks).
// ---------------------------------------------------------------------------
template <int OUT, bool RELU, bool GATE, bool PLUSONE, bool BIAS>
__device__ __forceinline__ void fwd_stage(
    const float* __restrict__ W, const float* __restrict__ bias,
    const float* __restrict__ hist, const float* __restrict__ Darr,
    const float* __restrict__ tg, float* __restrict__ outv,
    int b, int hc, int t, float lr,
    float* s_in, float* s_c, float* s_corr,
    int tid, int lane, int w)
{
    s_in[tid]       = hist[(b * TT + t) * HH + tid];
    s_in[tid + 256] = hist[(b * TT + t) * HH + tid + 256];
    __syncthreads();

    for (int s = w; s < t; s += 4) {
        const float4 h0 = *(const float4*)&hist[(b * TT + s) * HH + lane * 8];
        const float4 h1 = *(const float4*)&hist[(b * TT + s) * HH + lane * 8 + 4];
        float a = h0.x * s_in[lane * 8]     + h0.y * s_in[lane * 8 + 1] +
                  h0.z * s_in[lane * 8 + 2] + h0.w * s_in[lane * 8 + 3] +
                  h1.x * s_in[lane * 8 + 4] + h1.y * s_in[lane * 8 + 5] +
                  h1.z * s_in[lane * 8 + 6] + h1.w * s_in[lane * 8 + 7];
        a = wred(a);
        if (lane == 0) s_c[s] = a + (PLUSONE ? 1.0f : 0.0f);
    }
    __syncthreads();

    constexpr int RPW = OUT / 8;   // rows per WG: 64 (H) or 32 (Y)
    if (tid < RPW) {
        const int row = hc * RPW + tid;
        float cr = 0.0f;
        for (int s = 0; s < t; ++s) cr += Darr[(b * TT + s) * OUT + row] * s_c[s];
        s_corr[tid] = lr * cr;
    }
    __syncthreads();

    float xr[8];
    {
        const float4 a0 = *(const float4*)&s_in[lane * 8];
        const float4 a1 = *(const float4*)&s_in[lane * 8 + 4];
        xr[0] = a0.x; xr[1] = a0.y; xr[2] = a0.z; xr[3] = a0.w;
        xr[4] = a1.x; xr[5] = a1.y; xr[6] = a1.z; xr[7] = a1.w;
    }
    constexpr int RPL = RPW / 4;   // rows per wave: 16 or 8
    for (int r = 0; r < RPL; ++r) {
        const int row = hc * RPW + w * RPL + r;
        const float4 w0 = *(const float4*)&W[row * HH + lane * 8];
        const float4 w1 = *(const float4*)&W[row * HH + lane * 8 + 4];
        float a = w0.x * xr[0] + w0.y * xr[1] + w0.z * xr[2] + w0.w * xr[3] +
                  w1.x * xr[4] + w1.y * xr[5] + w1.z * xr[6] + w1.w * xr[7];
        a = wred(a);
        if (lane == 0) {
            float v = a - s_corr[w * RPL + r];
            if constexpr (BIAS) v += bias[row];
            if constexpr (RELU) v = fmaxf(v, 0.0f);
            if constexpr (GATE) v *= tg[(b * TT + t) * HH + row];
            outv[row] = v;
        }
    }
}

__device__ __forceinline__ void bwd4_stage(
    const float* __restrict__ W4, const float* __restrict__ ty,
    const float* __restrict__ tg, const float* __restrict__ LOG,
    const float* __restrict__ HG, float* __restrict__ D4,
    float* __restrict__ D3,
    int b, int hc, int t, float lr,
    float* s_dlg, float* s_c, float (*s_part)[64],
    int tid, int lane, int w)
{
    s_dlg[tid] = (LOG[b * YY + tid] - ty[(b * TT + t) * YY + tid]) * (2.0f / YY);
    __syncthreads();
    if (hc == 0) D4[(b * TT + t) * YY + tid] = s_dlg[tid];

    for (int s = w; s < t; s += 4) {
        const float4 d0 = *(const float4*)&D4[(b * TT + s) * YY + lane * 4];
        float a = d0.x * s_dlg[lane * 4]     + d0.y * s_dlg[lane * 4 + 1] +
                  d0.z * s_dlg[lane * 4 + 2] + d0.w * s_dlg[lane * 4 + 3];
        a = wred(a);
        if (lane == 0) s_c[s] = lr * a;
    }
    __syncthreads();

    const int h = hc * 64 + lane;
    float acc = 0.0f;
    for (int y = w * 64; y < w * 64 + 64; ++y) acc += W4[y * HH + h] * s_dlg[y];
    s_part[w][lane] = acc;
    __syncthreads();

    if (tid < 64) {
        const int hh = hc * 64 + tid;
        float sum = s_part[0][tid] + s_part[1][tid] + s_part[2][tid] + s_part[3][tid];
        for (int s = 0; s < t; ++s) sum -= HG[(b * TT + s) * HH + hh] * s_c[s];
        const float g = tg[(b * TT + t) * HH + hh];
        const float m = (HG[(b * TT + t) * HH + hh] > 0.0f) ? 1.0f : 0.0f;
        D3[(b * TT + t) * HH + hh] = sum * g * m;
    }
}

template <bool EPI>
__device__ __forceinline__ void bwd_stage(
    const float* __restrict__ W, const float* __restrict__ Din,
    const float* __restrict__ hist, float* __restrict__ Dout,
    const float* __restrict__ Z1base, const float* __restrict__ G1,
    float* __restrict__ H1,
    int b, int hc, int t, float lr,
    float* s_v, float* s_c, float (*s_part)[64], float* s_g,
    int tid, int lane, int w)
{
    s_v[tid]       = Din[(b * TT + t) * HH + tid];
    s_v[tid + 256] = Din[(b * TT + t) * HH + tid + 256];
    __syncthreads();

    for (int s = w; s < t; s += 4) {
        const float4 d0 = *(const float4*)&Din[(b * TT + s) * HH + lane * 8];
        const float4 d1 = *(const float4*)&Din[(b * TT + s) * HH + lane * 8 + 4];
        float a = d0.x * s_v[lane * 8]     + d0.y * s_v[lane * 8 + 1] +
                  d0.z * s_v[lane * 8 + 2] + d0.w * s_v[lane * 8 + 3] +
                  d1.x * s_v[lane * 8 + 4] + d1.y * s_v[lane * 8 + 5] +
                  d1.z * s_v[lane * 8 + 6] + d1.w * s_v[lane * 8 + 7];
        a = wred(a);
        if (lane == 0) s_c[s] = lr * a;
    }
    if (EPI && tid < TT)
        s_g[tid] = G1[(b * TT + tid) * TT + ((t + 1 < TT) ? (t + 1) : 0)];
    __syncthreads();

    const int h = hc * 64 + lane;
    float acc = 0.0f;
    for (int i = w * 128; i < w * 128 + 128; ++i) acc += W[i * HH + h] * s_v[i];
    s_part[w][lane] = acc;
    __syncthreads();

    if (tid < 64) {
        const int hh = hc * 64 + tid;
        float sum = s_part[0][tid] + s_part[1][tid] + s_part[2][tid] + s_part[3][tid];
        for (int s = 0; s < t; ++s) sum -= hist[(b * TT + s) * HH + hh] * s_c[s];
        const float m = (hist[(b * TT + t) * HH + hh] > 0.0f) ? 1.0f : 0.0f;
        const float dz = sum * m;
        Dout[(b * TT + t) * HH + hh] = dz;
        if (EPI && (t + 1 < TT)) {
            float cr = dz * s_g[t];
            for (int s = 0; s < t; ++s) cr += Dout[(b * TT + s) * HH + hh] * s_g[s];
            const float z = Z1base[(b * TT + t + 1) * HH + hh];
            H1[(b * TT + (t + 1)) * HH + hh] = fmaxf(z - lr * cr, 0.0f);
        }
    }
}

// ---------------------------------------------------------------------------
// Persistent inner-loop kernel: all T=16 steps x 6 stages, 96 grid barriers.
// grid: NWG=128 WGs of 256. WG = (b, hc).
// ---------------------------------------------------------------------------
__global__ __launch_bounds__(256) void k_inner(
    const float* __restrict__ W2, const float* __restrict__ b2,
    const float* __restrict__ W3, const float* __restrict__ b3,
    const float* __restrict__ W4, const float* __restrict__ ty,
    const float* __restrict__ tg,
    const float* __restrict__ Z1base, const float* __restrict__ G1,
    float* __restrict__ H1, float* __restrict__ H2, float* __restrict__ HG,
    float* __restrict__ D1, float* __restrict__ D2, float* __restrict__ D3,
    float* __restrict__ D4, float* __restrict__ LOG,
    const float* __restrict__ loglr, unsigned* __restrict__ bar)
{
    const int wid = blockIdx.x;
    const int b = wid >> 3, hc = wid & 7;
    const int tid = threadIdx.x, lane = tid & 63, w = tid >> 6;
    const float lr = expf(loglr[0]);

    __shared__ float s_vec[HH];
    __shared__ float s_c[TT];
    __shared__ float s_corr[64];
    __shared__ float s_part[4][64];
    __shared__ float s_g[TT];

    int bi = 0;
    for (int t = 0; t < TT; ++t) {
        // F2: h2 = relu(W2@h1 + b2 - lr*sum D2[s]*(h1_s.h1_t+1))
        fwd_stage<HH, true, false, true, true>(
            W2, b2, H1, D2, nullptr, H2 + (b * TT + t) * HH,
            b, hc, t, lr, s_vec, s_c, s_corr, tid, lane, w);
        gbar(bar, bi++);
        // F3: hg = relu(z3) * gate_t
        fwd_stage<HH, true, true, true, true>(
            W3, b3, H2, D3, tg, HG + (b * TT + t) * HH,
            b, hc, t, lr, s_vec, s_c, s_corr, tid, lane, w);
        gbar(bar, bi++);
        // F4: logit
        fwd_stage<YY, false, false, false, false>(
            W4, nullptr, HG, D4, nullptr, LOG + b * YY,
            b, hc, t, lr, s_vec, s_c, s_corr, tid, lane, w);
        gbar(bar, bi++);
        // B4 -> D4[b][t], D3[b][t]
        bwd4_stage(W4, ty, tg, LOG, HG, D4, D3,
                   b, hc, t, lr, s_vec, s_c, s_part, tid, lane, w);
        gbar(bar, bi++);
        // B3 -> D2[b][t]
        bwd_stage<false>(W3, D3, H2, D2, nullptr, nullptr, nullptr,
                         b, hc, t, lr, s_vec, s_c, s_part, s_g, tid, lane, w);
        gbar(bar, bi++);
        // B2 -> D1[b][t] + h1_{t+1}
        bwd_stage<true>(W2, D2, H1, D1, Z1base, G1, H1,
                        b, hc, t, lr, s_vec, s_c, s_part, s_g, tid, lane, w);
        gbar(bar, bi++);
    }
}

// ---------------------------------------------------------------------------
// Phase-2 inner products: ip[b][s][l] = A[b][s] . (act[b][l] *? tg[b][l]) (+1)
// ---------------------------------------------------------------------------
template <int K, bool PLUSONE, bool GATE>
__global__ __launch_bounds__(256) void k_ip(
    const float* __restrict__ A, const float* __restrict__ act,
    const float* __restrict__ tg, float* __restrict__ ip)
{
    const int b = blockIdx.x / TT, s = blockIdx.x % TT;
    const int tid = threadIdx.x, lane = tid & 63, w = tid >> 6;
    constexpr int E = K / 64;

    float ar[E];
    #pragma unroll
    for (int j = 0; j < E; j += 4) {
        const float4 v = *(const float4*)&A[(b * TT + s) * K + lane * E + j];
        ar[j] = v.x; ar[j + 1] = v.y; ar[j + 2] = v.z; ar[j + 3] = v.w;
    }
    for (int l0 = 0; l0 < 32; ++l0) {
        const int l = w * 32 + l0;
        float a = 0.0f;
        #pragma unroll
        for (int j = 0; j < E; j += 4) {
            const float4 v = *(const float4*)&act[((long)b * LL + l) * K + lane * E + j];
            float gx = 1.0f, gy = 1.0f, gz = 1.0f, gw = 1.0f;
            if constexpr (GATE) {
                const float4 g = *(const float4*)&tg[((long)b * LL + l) * K + lane * E + j];
                gx = g.x; gy = g.y; gz = g.z; gw = g.w;
            }
            a += v.x * gx * ar[j] + v.y * gy * ar[j + 1] +
                 v.z * gz * ar[j + 2] + v.w * gw * ar[j + 3];
        }
        a = wred(a);
        if (lane == 0) ip[(b * TT + s) * LL + l] = a + (PLUSONE ? 1.0f : 0.0f);
    }
}

// ---------------------------------------------------------------------------
// Phase-2 layer: out[b][l][n] = post( W@act + bias - lr*sum_s D[s][n]*ip[s][l] )
// ---------------------------------------------------------------------------
template <int K, int OUT, bool RELU, bool BIAS, bool GATEIN>
__global__ __launch_bounds__(256) void k_layer(
    const float* __restrict__ W, const float* __restrict__ bias,
    const float* __restrict__ act, const float* __restrict__ tg,
    const float* __restrict__ Dl, const float* __restrict__ ip,
    float* __restrict__ outp, const float* __restrict__ loglr)
{
    constexpr int NC = OUT / 64;
    const int blk = blockIdx.x;
    const int b = blk / (NC * 4);
    const int rem = blk % (NC * 4);
    const int nc = rem / 4, lc = rem % 4;
    const int base_n = nc * 64, base_l = lc * 32;
    const int tid = threadIdx.x;
    const int tn = tid & 31, tl = tid >> 5;
    const float lr = expf(loglr[0]);

    __shared__ float lw[64][65];
    __shared__ float lx[32][65];
    __shared__ float sD[TT][64];
    __shared__ float sip[TT][32];

    #pragma unroll
    for (int rep = 0; rep < 4; ++rep) {
        const int flat = rep * 256 + tid;
        const int s = flat >> 6, n = flat & 63;
        sD[s][n] = Dl[(b * TT + s) * OUT + base_n + n];
    }
    #pragma unroll
    for (int rep = 0; rep < 2; ++rep) {
        const int flat = rep * 256 + tid;
        const int s = flat >> 5, l = flat & 31;
        sip[s][l] = ip[(b * TT + s) * LL + base_l + l];
    }

    float acc[2][4] = {};
    for (int kc = 0; kc < K; kc += 64) {
        __syncthreads();
        #pragma unroll
        for (int rep = 0; rep < 16; ++rep) {
            const int flat = rep * 256 + tid;
            const int i = flat >> 6, k = flat & 63;
            lw[i][k] = W[(base_n + i) * K + kc + k];
        }
        #pragma unroll
        for (int rep = 0; rep < 8; ++rep) {
            const int flat = rep * 256 + tid;
            const int l = flat >> 6, k = flat & 63;
            float v = act[((long)b * LL + base_l + l) * K + kc + k];
            if constexpr (GATEIN)
                v *= tg[((long)b * LL + base_l + l) * K + kc + k];
            lx[l][k] = v;
        }
        __syncthreads();
        #pragma unroll 4
        for (int k = 0; k < 64; ++k) {
            const float w0 = lw[tn][k], w1 = lw[tn + 32][k];
            const float x0 = lx[tl][k],      x1 = lx[tl + 8][k];
            const float x2 = lx[tl + 16][k], x3 = lx[tl + 24][k];
            acc[0][0] += w0 * x0; acc[0][1] += w0 * x1;
            acc[0][2] += w0 * x2; acc[0][3] += w0 * x3;
            acc[1][0] += w1 * x0; acc[1][1] += w1 * x1;
            acc[1][2] += w1 * x2; acc[1][3] += w1 * x3;
        }
    }

    #pragma unroll
    for (int i = 0; i < 2; ++i) {
        const int n = base_n + tn + i * 32;
        const float bv = BIAS ? bias[n] : 0.0f;
        #pragma unroll
        for (int j = 0; j < 4; ++j) {
            const int l = base_l + tl + j * 8;
            float corr = 0.0f;
            #pragma unroll
            for (int s = 0; s < TT; ++s)
                corr += sD[s][tn + i * 32] * sip[s][tl + j * 8];
            float v = acc[i][j] + bv - lr * corr;
            if constexpr (RELU) v = fmaxf(v, 0.0f);
            outp[((long)b * LL + l) * OUT + n] = v;
        }
    }
}

// ---------------------------------------------------------------------------
__global__ __launch_bounds__(64) void k_loss(
    const float* __restrict__ logit, const float* __restrict__ tey,
    float* __restrict__ loss, float* __restrict__ evalo)
{
    const int idx = blockIdx.x;
    const int lane = threadIdx.x;
    float a = 0.0f;
    #pragma unroll
    for (int j = 0; j < 4; ++j) {
        const float d = logit[(long)idx * YY + lane * 4 + j] -
                        tey[(long)idx * YY + lane * 4 + j];
        a += d * d;
    }
    a = wred(a);
    if (lane == 0) {
        const float v = a * (1.0f / YY);
        loss[idx] = v;
        evalo[idx] = v;
    }
}

// ---------------------------------------------------------------------------
extern "C" void kernel_launch(void* const* d_in, const int* in_sizes, int n_in,
                              void* d_out, int out_size, void* d_ws, size_t ws_size,
                              hipStream_t stream)
{
    const float* tx    = (const float*)d_in[0];
    const float* ty    = (const float*)d_in[1];
    const float* tex   = (const float*)d_in[2];
    const float* tey   = (const float*)d_in[3];
    const float* tg    = (const float*)d_in[4];
    const float* teg   = (const float*)d_in[5];
    const float* W1    = (const float*)d_in[6];
    const float* b1    = (const float*)d_in[7];
    const float* W2    = (const float*)d_in[8];
    const float* b2    = (const float*)d_in[9];
    const float* W3    = (const float*)d_in[10];
    const float* b3    = (const float*)d_in[11];
    const float* W4    = (const float*)d_in[12];
    const float* loglr = (const float*)d_in[13];

    float* out = (float*)d_out;
    float* ws  = (float*)d_ws;

    // workspace layout (floats)
    float* Z1base = ws;                 // 131072
    float* G1     = ws + 131072;        // 4096
    float* H1     = ws + 135168;        // 131072
    float* H2     = ws + 266240;        // 131072
    float* HG     = ws + 397312;        // 131072
    float* D1     = ws + 528384;        // 131072
    float* D2     = ws + 659456;        // 131072
    float* D3     = ws + 790528;        // 131072
    float* D4     = ws + 921600;        // 65536
    float* LOG    = ws + 987136;        // 4096
    float* IP     = ws + 991232;        // 32768
    float* ActA   = ws + 1024000;       // 1048576
    float* ActB   = ws + 2072576;       // 1048576
    unsigned* bar = (unsigned*)(ws + 3121152);  // 128 barrier counters

    hipMemsetAsync(bar, 0, 128 * sizeof(unsigned), stream);

    k_z1<<<64, 256, 0, stream>>>(W1, b1, tx, Z1base, H1);
    k_gram<<<TB, 256, 0, stream>>>(tx, loglr, G1, out);

    k_inner<<<NWG, 256, 0, stream>>>(W2, b2, W3, b3, W4, ty, tg,
                                     Z1base, G1, H1, H2, HG,
                                     D1, D2, D3, D4, LOG, loglr, bar);

    // ---- Phase 2: test-set forward with final (rank-16-corrected) weights ----
    k_ip<XX, true, false><<<TB * TT, 256, 0, stream>>>(tx, tex, nullptr, IP);
    k_layer<XX, HH, true, true, false><<<TB * 8 * 4, 256, 0, stream>>>(
        W1, b1, tex, nullptr, D1, IP, ActA, loglr);

    k_ip<HH, true, false><<<TB * TT, 256, 0, stream>>>(H1, ActA, nullptr, IP);
    k_layer<HH, HH, true, true, false><<<TB * 8 * 4, 256, 0, stream>>>(
        W2, b2, ActA, nullptr, D2, IP, ActB, loglr);

    k_ip<HH, true, false><<<TB * TT, 256, 0, stream>>>(H2, ActB, nullptr, IP);
    k_layer<HH, HH, true, true, false><<<TB * 8 * 4, 256, 0, stream>>>(
        W3, b3, ActB, nullptr, D3, IP, ActA, loglr);

    k_ip<HH, false, true><<<TB * TT, 256, 0, stream>>>(HG, ActA, teg, IP);
    k_layer<HH, YY, false, false, true><<<TB * 4 * 4, 256, 0, stream>>>(
        W4, nullptr, ActA, teg, D4, IP, out + 4097, loglr);

    k_loss<<<TB * LL, 64, 0, stream>>>(out + 4097, tey, out, out + 2049);
}

// Round 3
// 1555.562 us; speedup vs baseline: 1.2600x; 1.2600x over previous
//
#include <hip/hip_runtime.h>
#include <math.h>

// Problem dims
#define TB 16   // batch (tasks)
#define TT 16   // train steps
#define LL 128  // test length
#define XX 256  // x dim
#define HH 512  // hidden
#define YY 256  // y dim

__device__ __forceinline__ float wred(float v) {
    v += __shfl_xor(v, 32);
    v += __shfl_xor(v, 16);
    v += __shfl_xor(v, 8);
    v += __shfl_xor(v, 4);
    v += __shfl_xor(v, 2);
    v += __shfl_xor(v, 1);
    return v;
}

// Per-example grid barrier: 8 WGs of one example arrive on a private counter
// line (counters for different examples are 512B apart -> no false sharing,
// parallel across 16 lines). Relaxed spin + one acquire fence at the end.
__device__ __forceinline__ void gbar8(unsigned* cnt) {
    __syncthreads();
    if (threadIdx.x == 0) {
        __threadfence();  // release: drain + make prior stores agent-visible
        __hip_atomic_fetch_add(cnt, 1u, __ATOMIC_RELAXED,
                               __HIP_MEMORY_SCOPE_AGENT);
        while (__hip_atomic_load(cnt, __ATOMIC_RELAXED,
                                 __HIP_MEMORY_SCOPE_AGENT) < 8u)
            __builtin_amdgcn_s_sleep(2);
        __builtin_amdgcn_fence(__ATOMIC_ACQUIRE, "agent");
    }
    __syncthreads();
}

// ---------------------------------------------------------------------------
// Z1 = train_x @ W1^T + b1 as a tiled GEMM  [256 m] x [512 n] x [256 k]
// epilogue: H1[b][0] = relu(Z1[b][0]).  grid: 64 WGs of 256.
// ---------------------------------------------------------------------------
__global__ __launch_bounds__(256) void k_z1(
    const float* __restrict__ W1, const float* __restrict__ b1,
    const float* __restrict__ tx, float* __restrict__ Z1base,
    float* __restrict__ H1)
{
    const int nc = blockIdx.x & 7, mc = blockIdx.x >> 3;
    const int tid = threadIdx.x;
    const int tn = tid & 31, tl = tid >> 5;
    __shared__ float lw[64][65];
    __shared__ float lx[32][65];
    float acc[2][4] = {};
    for (int kc = 0; kc < XX; kc += 64) {
        __syncthreads();
        #pragma unroll
        for (int rep = 0; rep < 16; ++rep) {
            const int flat = rep * 256 + tid;
            const int i = flat >> 6, k = flat & 63;
            lw[i][k] = W1[(nc * 64 + i) * XX + kc + k];
        }
        #pragma unroll
        for (int rep = 0; rep < 8; ++rep) {
            const int flat = rep * 256 + tid;
            const int l = flat >> 6, k = flat & 63;
            lx[l][k] = tx[(mc * 32 + l) * XX + kc + k];
        }
        __syncthreads();
        #pragma unroll 4
        for (int k = 0; k < 64; ++k) {
            const float w0 = lw[tn][k], w1 = lw[tn + 32][k];
            const float x0 = lx[tl][k],      x1 = lx[tl + 8][k];
            const float x2 = lx[tl + 16][k], x3 = lx[tl + 24][k];
            acc[0][0] += w0 * x0; acc[0][1] += w0 * x1;
            acc[0][2] += w0 * x2; acc[0][3] += w0 * x3;
            acc[1][0] += w1 * x0; acc[1][1] += w1 * x1;
            acc[1][2] += w1 * x2; acc[1][3] += w1 * x3;
        }
    }
    #pragma unroll
    for (int i = 0; i < 2; ++i) {
        const int n = nc * 64 + tn + i * 32;
        const float bv = b1[n];
        #pragma unroll
        for (int j = 0; j < 4; ++j) {
            const int m = mc * 32 + tl + j * 8;
            const float v = acc[i][j] + bv;
            Z1base[m * HH + n] = v;
            if ((m & 15) == 0) H1[m * HH + n] = fmaxf(v, 0.0f);  // t==0
        }
    }
}

// ---------------------------------------------------------------------------
// Gram: G1[b][s][t] = x_s.x_t + 1 ; also out[2048] = exp(loglr).
// grid: B blocks of 256 (thread = (s,t) pair).
// ---------------------------------------------------------------------------
__global__ __launch_bounds__(256) void k_gram(
    const float* __restrict__ tx, const float* __restrict__ loglr,
    float* __restrict__ G1, float* __restrict__ out)
{
    const int b = blockIdx.x;
    const int tid = threadIdx.x;
    __shared__ float sx[TT][XX + 1];
    #pragma unroll
    for (int rep = 0; rep < 16; ++rep) {
        const int flat = rep * 256 + tid;
        const int s = flat >> 8, k = flat & 255;
        sx[s][k] = tx[(b * TT + s) * XX + k];
    }
    __syncthreads();
    if (b == 0 && tid == 0) out[2048] = expf(loglr[0]);
    const int s = tid >> 4, t = tid & 15;
    float a = 0.0f;
    #pragma unroll 8
    for (int k = 0; k < XX; ++k) a += sx[s][k] * sx[t][k];
    G1[(b * TT + s) * TT + t] = a + 1.0f;
}

// ---------------------------------------------------------------------------
// Stage device functions for the persistent inner-loop kernel.
// WG = (b, hc): example b, row-chunk hc (8 chunks).
// ---------------------------------------------------------------------------
template <int OUT, bool RELU, bool GATE, bool PLUSONE, bool BIAS>
__device__ __forceinline__ void fwd_stage(
    const float* __restrict__ W, const float* __restrict__ bias,
    const float* __restrict__ hist, const float* __restrict__ Darr,
    const float* __restrict__ tg, float* __restrict__ outv,
    int b, int hc, int t, float lr,
    float* s_in, float* s_c, float* s_corr,
    int tid, int lane, int w)
{
    s_in[tid]       = hist[(b * TT + t) * HH + tid];
    s_in[tid + 256] = hist[(b * TT + t) * HH + tid + 256];
    __syncthreads();

    for (int s = w; s < t; s += 4) {
        const float4 h0 = *(const float4*)&hist[(b * TT + s) * HH + lane * 8];
        const float4 h1 = *(const float4*)&hist[(b * TT + s) * HH + lane * 8 + 4];
        float a = h0.x * s_in[lane * 8]     + h0.y * s_in[lane * 8 + 1] +
                  h0.z * s_in[lane * 8 + 2] + h0.w * s_in[lane * 8 + 3] +
                  h1.x * s_in[lane * 8 + 4] + h1.y * s_in[lane * 8 + 5] +
                  h1.z * s_in[lane * 8 + 6] + h1.w * s_in[lane * 8 + 7];
        a = wred(a);
        if (lane == 0) s_c[s] = a + (PLUSONE ? 1.0f : 0.0f);
    }
    __syncthreads();

    constexpr int RPW = OUT / 8;   // rows per WG: 64 (H) or 32 (Y)
    if (tid < RPW) {
        const int row = hc * RPW + tid;
        float cr = 0.0f;
        for (int s = 0; s < t; ++s) cr += Darr[(b * TT + s) * OUT + row] * s_c[s];
        s_corr[tid] = lr * cr;
    }
    __syncthreads();

    float xr[8];
    {
        const float4 a0 = *(const float4*)&s_in[lane * 8];
        const float4 a1 = *(const float4*)&s_in[lane * 8 + 4];
        xr[0] = a0.x; xr[1] = a0.y; xr[2] = a0.z; xr[3] = a0.w;
        xr[4] = a1.x; xr[5] = a1.y; xr[6] = a1.z; xr[7] = a1.w;
    }
    constexpr int RPL = RPW / 4;   // rows per wave: 16 or 8
    for (int r = 0; r < RPL; ++r) {
        const int row = hc * RPW + w * RPL + r;
        const float4 w0 = *(const float4*)&W[row * HH + lane * 8];
        const float4 w1 = *(const float4*)&W[row * HH + lane * 8 + 4];
        float a = w0.x * xr[0] + w0.y * xr[1] + w0.z * xr[2] + w0.w * xr[3] +
                  w1.x * xr[4] + w1.y * xr[5] + w1.z * xr[6] + w1.w * xr[7];
        a = wred(a);
        if (lane == 0) {
            float v = a - s_corr[w * RPL + r];
            if constexpr (BIAS) v += bias[row];
            if constexpr (RELU) v = fmaxf(v, 0.0f);
            if constexpr (GATE) v *= tg[(b * TT + t) * HH + row];
            outv[row] = v;
        }
    }
}

__device__ __forceinline__ void bwd4_stage(
    const float* __restrict__ W4, const float* __restrict__ ty,
    const float* __restrict__ tg, const float* __restrict__ LOG,
    const float* __restrict__ HG, float* __restrict__ D4,
    float* __restrict__ D3,
    int b, int hc, int t, float lr,
    float* s_dlg, float* s_c, float (*s_part)[64],
    int tid, int lane, int w)
{
    s_dlg[tid] = (LOG[b * YY + tid] - ty[(b * TT + t) * YY + tid]) * (2.0f / YY);
    __syncthreads();
    if (hc == 0) D4[(b * TT + t) * YY + tid] = s_dlg[tid];

    for (int s = w; s < t; s += 4) {
        const float4 d0 = *(const float4*)&D4[(b * TT + s) * YY + lane * 4];
        float a = d0.x * s_dlg[lane * 4]     + d0.y * s_dlg[lane * 4 + 1] +
                  d0.z * s_dlg[lane * 4 + 2] + d0.w * s_dlg[lane * 4 + 3];
        a = wred(a);
        if (lane == 0) s_c[s] = lr * a;
    }
    __syncthreads();

    const int h = hc * 64 + lane;
    float acc = 0.0f;
    for (int y = w * 64; y < w * 64 + 64; ++y) acc += W4[y * HH + h] * s_dlg[y];
    s_part[w][lane] = acc;
    __syncthreads();

    if (tid < 64) {
        const int hh = hc * 64 + tid;
        float sum = s_part[0][tid] + s_part[1][tid] + s_part[2][tid] + s_part[3][tid];
        for (int s = 0; s < t; ++s) sum -= HG[(b * TT + s) * HH + hh] * s_c[s];
        const float g = tg[(b * TT + t) * HH + hh];
        const float m = (HG[(b * TT + t) * HH + hh] > 0.0f) ? 1.0f : 0.0f;
        D3[(b * TT + t) * HH + hh] = sum * g * m;
    }
}

template <bool EPI>
__device__ __forceinline__ void bwd_stage(
    const float* __restrict__ W, const float* __restrict__ Din,
    const float* __restrict__ hist, float* __restrict__ Dout,
    const float* __restrict__ Z1base, const float* __restrict__ G1,
    float* __restrict__ H1,
    int b, int hc, int t, float lr,
    float* s_v, float* s_c, float (*s_part)[64], float* s_g,
    int tid, int lane, int w)
{
    s_v[tid]       = Din[(b * TT + t) * HH + tid];
    s_v[tid + 256] = Din[(b * TT + t) * HH + tid + 256];
    __syncthreads();

    for (int s = w; s < t; s += 4) {
        const float4 d0 = *(const float4*)&Din[(b * TT + s) * HH + lane * 8];
        const float4 d1 = *(const float4*)&Din[(b * TT + s) * HH + lane * 8 + 4];
        float a = d0.x * s_v[lane * 8]     + d0.y * s_v[lane * 8 + 1] +
                  d0.z * s_v[lane * 8 + 2] + d0.w * s_v[lane * 8 + 3] +
                  d1.x * s_v[lane * 8 + 4] + d1.y * s_v[lane * 8 + 5] +
                  d1.z * s_v[lane * 8 + 6] + d1.w * s_v[lane * 8 + 7];
        a = wred(a);
        if (lane == 0) s_c[s] = lr * a;
    }
    if (EPI && tid < TT)
        s_g[tid] = G1[(b * TT + tid) * TT + ((t + 1 < TT) ? (t + 1) : 0)];
    __syncthreads();

    const int h = hc * 64 + lane;
    float acc = 0.0f;
    for (int i = w * 128; i < w * 128 + 128; ++i) acc += W[i * HH + h] * s_v[i];
    s_part[w][lane] = acc;
    __syncthreads();

    if (tid < 64) {
        const int hh = hc * 64 + tid;
        float sum = s_part[0][tid] + s_part[1][tid] + s_part[2][tid] + s_part[3][tid];
        for (int s = 0; s < t; ++s) sum -= hist[(b * TT + s) * HH + hh] * s_c[s];
        const float m = (hist[(b * TT + t) * HH + hh] > 0.0f) ? 1.0f : 0.0f;
        const float dz = sum * m;
        Dout[(b * TT + t) * HH + hh] = dz;
        if (EPI && (t + 1 < TT)) {
            float cr = dz * s_g[t];
            for (int s = 0; s < t; ++s) cr += Dout[(b * TT + s) * HH + hh] * s_g[s];
            const float z = Z1base[(b * TT + t + 1) * HH + hh];
            H1[(b * TT + (t + 1)) * HH + hh] = fmaxf(z - lr * cr, 0.0f);
        }
    }
}

// ---------------------------------------------------------------------------
// Persistent inner-loop kernel: T=16 steps x 6 stages, 96 PER-EXAMPLE barriers.
// grid: 128 WGs of 256. WG = (b, hc); barrier groups are the 8 WGs of one b.
// ---------------------------------------------------------------------------
__global__ __launch_bounds__(256) void k_inner(
    const float* __restrict__ W2, const float* __restrict__ b2,
    const float* __restrict__ W3, const float* __restrict__ b3,
    const float* __restrict__ W4, const float* __restrict__ ty,
    const float* __restrict__ tg,
    const float* __restrict__ Z1base, const float* __restrict__ G1,
    float* __restrict__ H1, float* __restrict__ H2, float* __restrict__ HG,
    float* __restrict__ D1, float* __restrict__ D2, float* __restrict__ D3,
    float* __restrict__ D4, float* __restrict__ LOG,
    const float* __restrict__ loglr, unsigned* __restrict__ bar)
{
    const int wid = blockIdx.x;
    const int b = wid >> 3, hc = wid & 7;
    const int tid = threadIdx.x, lane = tid & 63, w = tid >> 6;
    const float lr = expf(loglr[0]);
    unsigned* mybar = bar + b * 128;   // 512B-aligned private line per example

    __shared__ float s_vec[HH];
    __shared__ float s_c[TT];
    __shared__ float s_corr[64];
    __shared__ float s_part[4][64];
    __shared__ float s_g[TT];

    int bi = 0;
    for (int t = 0; t < TT; ++t) {
        // F2: h2 = relu(W2@h1 + b2 - lr*sum D2[s]*(h1_s.h1_t+1))
        fwd_stage<HH, true, false, true, true>(
            W2, b2, H1, D2, nullptr, H2 + (b * TT + t) * HH,
            b, hc, t, lr, s_vec, s_c, s_corr, tid, lane, w);
        gbar8(&mybar[bi++]);
        // F3: hg = relu(z3) * gate_t
        fwd_stage<HH, true, true, true, true>(
            W3, b3, H2, D3, tg, HG + (b * TT + t) * HH,
            b, hc, t, lr, s_vec, s_c, s_corr, tid, lane, w);
        gbar8(&mybar[bi++]);
        // F4: logit
        fwd_stage<YY, false, false, false, false>(
            W4, nullptr, HG, D4, nullptr, LOG + b * YY,
            b, hc, t, lr, s_vec, s_c, s_corr, tid, lane, w);
        gbar8(&mybar[bi++]);
        // B4 -> D4[b][t], D3[b][t]
        bwd4_stage(W4, ty, tg, LOG, HG, D4, D3,
                   b, hc, t, lr, s_vec, s_c, s_part, tid, lane, w);
        gbar8(&mybar[bi++]);
        // B3 -> D2[b][t]
        bwd_stage<false>(W3, D3, H2, D2, nullptr, nullptr, nullptr,
                         b, hc, t, lr, s_vec, s_c, s_part, s_g, tid, lane, w);
        gbar8(&mybar[bi++]);
        // B2 -> D1[b][t] + h1_{t+1}
        bwd_stage<true>(W2, D2, H1, D1, Z1base, G1, H1,
                        b, hc, t, lr, s_vec, s_c, s_part, s_g, tid, lane, w);
        gbar8(&mybar[bi++]);
    }
}

// ---------------------------------------------------------------------------
// Phase-2 layer with FUSED ip computation:
// sip[s][l] = A[b][s] . (act[b][l] *? tg[b][l]) (+1)
// out[b][l][n] = post( W@actg + bias - lr*sum_s D[s][n]*sip[s][l] )
// tile: 64 n x 32 l per WG.  grid: B*(OUT/64)*(L/32) blocks of 256
// ---------------------------------------------------------------------------
template <int K, int OUT, bool RELU, bool BIAS, bool GATEIN, bool PLUSONE>
__global__ __launch_bounds__(256) void k_layer(
    const float* __restrict__ W, const float* __restrict__ bias,
    const float* __restrict__ act, const float* __restrict__ tg,
    const float* __restrict__ A, const float* __restrict__ Dl,
    float* __restrict__ outp, const float* __restrict__ loglr)
{
    constexpr int NC = OUT / 64;
    constexpr int E = K / 64;
    const int blk = blockIdx.x;
    const int b = blk / (NC * 4);
    const int rem = blk % (NC * 4);
    const int nc = rem / 4, lc = rem % 4;
    const int base_n = nc * 64, base_l = lc * 32;
    const int tid = threadIdx.x;
    const int tn = tid & 31, tl = tid >> 5;
    const int lane = tid & 63, wv = tid >> 6;
    const float lr = expf(loglr[0]);

    __shared__ float lw[64][65];
    __shared__ float lx[32][65];
    __shared__ float sD[TT][64];
    __shared__ float sip[TT][33];

    #pragma unroll
    for (int rep = 0; rep < 4; ++rep) {
        const int flat = rep * 256 + tid;
        const int s = flat >> 6, n = flat & 63;
        sD[s][n] = Dl[(b * TT + s) * OUT + base_n + n];
    }

    // fused ip: wave wv handles s = wv, wv+4, wv+8, wv+12
    for (int s = wv; s < TT; s += 4) {
        float ar[E];
        #pragma unroll
        for (int j = 0; j < E; j += 4) {
            const float4 v = *(const float4*)&A[((long)b * TT + s) * K + lane * E + j];
            ar[j] = v.x; ar[j + 1] = v.y; ar[j + 2] = v.z; ar[j + 3] = v.w;
        }
        for (int l = 0; l < 32; ++l) {
            const float* ap = &act[((long)b * LL + base_l + l) * K + lane * E];
            float a = 0.0f;
            #pragma unroll
            for (int j = 0; j < E; j += 4) {
                const float4 v = *(const float4*)&ap[j];
                if constexpr (GATEIN) {
                    const float4 g = *(const float4*)
                        &tg[((long)b * LL + base_l + l) * K + lane * E + j];
                    a += v.x * g.x * ar[j]     + v.y * g.y * ar[j + 1] +
                         v.z * g.z * ar[j + 2] + v.w * g.w * ar[j + 3];
                } else {
                    a += v.x * ar[j]     + v.y * ar[j + 1] +
                         v.z * ar[j + 2] + v.w * ar[j + 3];
                }
            }
            a = wred(a);
            if (lane == 0) sip[s][l] = a + (PLUSONE ? 1.0f : 0.0f);
        }
    }

    float acc[2][4] = {};
    for (int kc = 0; kc < K; kc += 64) {
        __syncthreads();
        #pragma unroll
        for (int rep = 0; rep < 16; ++rep) {
            const int flat = rep * 256 + tid;
            const int i = flat >> 6, k = flat & 63;
            lw[i][k] = W[(base_n + i) * K + kc + k];
        }
        #pragma unroll
        for (int rep = 0; rep < 8; ++rep) {
            const int flat = rep * 256 + tid;
            const int l = flat >> 6, k = flat & 63;
            float v = act[((long)b * LL + base_l + l) * K + kc + k];
            if constexpr (GATEIN)
                v *= tg[((long)b * LL + base_l + l) * K + kc + k];
            lx[l][k] = v;
        }
        __syncthreads();
        #pragma unroll 4
        for (int k = 0; k < 64; ++k) {
            const float w0 = lw[tn][k], w1 = lw[tn + 32][k];
            const float x0 = lx[tl][k],      x1 = lx[tl + 8][k];
            const float x2 = lx[tl + 16][k], x3 = lx[tl + 24][k];
            acc[0][0] += w0 * x0; acc[0][1] += w0 * x1;
            acc[0][2] += w0 * x2; acc[0][3] += w0 * x3;
            acc[1][0] += w1 * x0; acc[1][1] += w1 * x1;
            acc[1][2] += w1 * x2; acc[1][3] += w1 * x3;
        }
    }

    #pragma unroll
    for (int i = 0; i < 2; ++i) {
        const int n = base_n + tn + i * 32;
        const float bv = BIAS ? bias[n] : 0.0f;
        #pragma unroll
        for (int j = 0; j < 4; ++j) {
            const int l = base_l + tl + j * 8;
            float corr = 0.0f;
            #pragma unroll
            for (int s = 0; s < TT; ++s)
                corr += sD[s][tn + i * 32] * sip[s][tl + j * 8];
            float v = acc[i][j] + bv - lr * corr;
            if constexpr (RELU) v = fmaxf(v, 0.0f);
            outp[((long)b * LL + l) * OUT + n] = v;
        }
    }
}

// ---------------------------------------------------------------------------
__global__ __launch_bounds__(64) void k_loss(
    const float* __restrict__ logit, const float* __restrict__ tey,
    float* __restrict__ loss, float* __restrict__ evalo)
{
    const int idx = blockIdx.x;
    const int lane = threadIdx.x;
    float a = 0.0f;
    #pragma unroll
    for (int j = 0; j < 4; ++j) {
        const float d = logit[(long)idx * YY + lane * 4 + j] -
                        tey[(long)idx * YY + lane * 4 + j];
        a += d * d;
    }
    a = wred(a);
    if (lane == 0) {
        const float v = a * (1.0f / YY);
        loss[idx] = v;
        evalo[idx] = v;
    }
}

// ---------------------------------------------------------------------------
extern "C" void kernel_launch(void* const* d_in, const int* in_sizes, int n_in,
                              void* d_out, int out_size, void* d_ws, size_t ws_size,
                              hipStream_t stream)
{
    const float* tx    = (const float*)d_in[0];
    const float* ty    = (const float*)d_in[1];
    const float* tex   = (const float*)d_in[2];
    const float* tey   = (const float*)d_in[3];
    const float* tg    = (const float*)d_in[4];
    const float* teg   = (const float*)d_in[5];
    const float* W1    = (const float*)d_in[6];
    const float* b1    = (const float*)d_in[7];
    const float* W2    = (const float*)d_in[8];
    const float* b2    = (const float*)d_in[9];
    const float* W3    = (const float*)d_in[10];
    const float* b3    = (const float*)d_in[11];
    const float* W4    = (const float*)d_in[12];
    const float* loglr = (const float*)d_in[13];

    float* out = (float*)d_out;
    float* ws  = (float*)d_ws;

    // workspace layout (floats)
    float* Z1base = ws;                 // 131072
    float* G1     = ws + 131072;        // 4096
    float* H1     = ws + 135168;        // 131072
    float* H2     = ws + 266240;        // 131072
    float* HG     = ws + 397312;        // 131072
    float* D1     = ws + 528384;        // 131072
    float* D2     = ws + 659456;        // 131072
    float* D3     = ws + 790528;        // 131072
    float* D4     = ws + 921600;        // 65536
    float* LOG    = ws + 987136;        // 4096
    unsigned* bar = (unsigned*)(ws + 991232);  // 16 x 128 counters (8KB)
    float* ActA   = ws + 1024000;       // 1048576
    float* ActB   = ws + 2072576;       // 1048576

    hipMemsetAsync(bar, 0, TB * 128 * sizeof(unsigned), stream);

    k_z1<<<64, 256, 0, stream>>>(W1, b1, tx, Z1base, H1);
    k_gram<<<TB, 256, 0, stream>>>(tx, loglr, G1, out);

    k_inner<<<128, 256, 0, stream>>>(W2, b2, W3, b3, W4, ty, tg,
                                     Z1base, G1, H1, H2, HG,
                                     D1, D2, D3, D4, LOG, loglr, bar);

    // ---- Phase 2: test-set forward with final (rank-16-corrected) weights ----
    k_layer<XX, HH, true, true, false, true><<<TB * 8 * 4, 256, 0, stream>>>(
        W1, b1, tex, nullptr, tx, D1, ActA, loglr);
    k_layer<HH, HH, true, true, false, true><<<TB * 8 * 4, 256, 0, stream>>>(
        W2, b2, ActA, nullptr, H1, D2, ActB, loglr);
    k_layer<HH, HH, true, true, false, true><<<TB * 8 * 4, 256, 0, stream>>>(
        W3, b3, ActB, nullptr, H2, D3, ActA, loglr);
    k_layer<HH, YY, false, false, true, false><<<TB * 4 * 4, 256, 0, stream>>>(
        W4, nullptr, ActA, teg, HG, D4, out + 4097, loglr);

    k_loss<<<TB * LL, 64, 0, stream>>>(out + 4097, tey, out, out + 2049);
}

// Round 4
// 1393.104 us; speedup vs baseline: 1.4070x; 1.1166x over previous
//
#include <hip/hip_runtime.h>
#include <math.h>

// Problem dims
#define TB 16   // batch (tasks)
#define TT 16   // train steps
#define LL 128  // test length
#define XX 256  // x dim
#define HH 512  // hidden
#define YY 256  // y dim

__device__ __forceinline__ float wred(float v) {
    v += __shfl_xor(v, 32);
    v += __shfl_xor(v, 16);
    v += __shfl_xor(v, 8);
    v += __shfl_xor(v, 4);
    v += __shfl_xor(v, 2);
    v += __shfl_xor(v, 1);
    return v;
}

// Coherent (agent-scope, write-through-to-MALL) store for cross-WG data.
// Single global_store with sc bits; no fence cache-ops anywhere.
__device__ __forceinline__ void stg(float* p, float v) {
    __hip_atomic_store(p, v, __ATOMIC_RELAXED, __HIP_MEMORY_SCOPE_AGENT);
}

// Fence-free per-example barrier. 8 WGs of one example each own a flag slot
// (64B apart in one 512B example line). Arrival = store monotonically
// increasing stage number (ordered after data stores by the vmcnt(0) drain
// the compiler emits before s_barrier in __syncthreads). Wait = 8 lanes poll
// the 8 slots in parallel with relaxed agent loads (bypass L2 -> see MALL).
// No threadfence -> no buffer_wbl2 / buffer_inv -> L2 stays warm.
__device__ __forceinline__ void gbar8(unsigned* slots, int hc, unsigned target) {
    __syncthreads();   // all waves' prior stores vmcnt-drained here
    if (threadIdx.x < 8) {
        if (threadIdx.x == hc)
            __hip_atomic_store(&slots[hc * 16], target, __ATOMIC_RELAXED,
                               __HIP_MEMORY_SCOPE_AGENT);
        while (__hip_atomic_load(&slots[threadIdx.x * 16], __ATOMIC_RELAXED,
                                 __HIP_MEMORY_SCOPE_AGENT) < target)
            __builtin_amdgcn_s_sleep(1);
    }
    __atomic_signal_fence(__ATOMIC_ACQ_REL);  // compiler-only ordering
    __syncthreads();
}

// ---------------------------------------------------------------------------
// Z1 = train_x @ W1^T + b1 as a tiled GEMM  [256 m] x [512 n] x [256 k]
// epilogue: H1[b][0] = relu(Z1[b][0]).  grid: 64 WGs of 256.
// ---------------------------------------------------------------------------
__global__ __launch_bounds__(256) void k_z1(
    const float* __restrict__ W1, const float* __restrict__ b1,
    const float* __restrict__ tx, float* __restrict__ Z1base,
    float* __restrict__ H1)
{
    const int nc = blockIdx.x & 7, mc = blockIdx.x >> 3;
    const int tid = threadIdx.x;
    const int tn = tid & 31, tl = tid >> 5;
    __shared__ float lw[64][65];
    __shared__ float lx[32][65];
    float acc[2][4] = {};
    for (int kc = 0; kc < XX; kc += 64) {
        __syncthreads();
        #pragma unroll
        for (int rep = 0; rep < 16; ++rep) {
            const int flat = rep * 256 + tid;
            const int i = flat >> 6, k = flat & 63;
            lw[i][k] = W1[(nc * 64 + i) * XX + kc + k];
        }
        #pragma unroll
        for (int rep = 0; rep < 8; ++rep) {
            const int flat = rep * 256 + tid;
            const int l = flat >> 6, k = flat & 63;
            lx[l][k] = tx[(mc * 32 + l) * XX + kc + k];
        }
        __syncthreads();
        #pragma unroll 4
        for (int k = 0; k < 64; ++k) {
            const float w0 = lw[tn][k], w1 = lw[tn + 32][k];
            const float x0 = lx[tl][k],      x1 = lx[tl + 8][k];
            const float x2 = lx[tl + 16][k], x3 = lx[tl + 24][k];
            acc[0][0] += w0 * x0; acc[0][1] += w0 * x1;
            acc[0][2] += w0 * x2; acc[0][3] += w0 * x3;
            acc[1][0] += w1 * x0; acc[1][1] += w1 * x1;
            acc[1][2] += w1 * x2; acc[1][3] += w1 * x3;
        }
    }
    #pragma unroll
    for (int i = 0; i < 2; ++i) {
        const int n = nc * 64 + tn + i * 32;
        const float bv = b1[n];
        #pragma unroll
        for (int j = 0; j < 4; ++j) {
            const int m = mc * 32 + tl + j * 8;
            const float v = acc[i][j] + bv;
            Z1base[m * HH + n] = v;
            if ((m & 15) == 0) H1[m * HH + n] = fmaxf(v, 0.0f);  // t==0
        }
    }
}

// ---------------------------------------------------------------------------
// Gram: G1[b][s][t] = x_s.x_t + 1 ; also out[2048] = exp(loglr).
// ---------------------------------------------------------------------------
__global__ __launch_bounds__(256) void k_gram(
    const float* __restrict__ tx, const float* __restrict__ loglr,
    float* __restrict__ G1, float* __restrict__ out)
{
    const int b = blockIdx.x;
    const int tid = threadIdx.x;
    __shared__ float sx[TT][XX + 1];
    #pragma unroll
    for (int rep = 0; rep < 16; ++rep) {
        const int flat = rep * 256 + tid;
        const int s = flat >> 8, k = flat & 255;
        sx[s][k] = tx[(b * TT + s) * XX + k];
    }
    __syncthreads();
    if (b == 0 && tid == 0) out[2048] = expf(loglr[0]);
    const int s = tid >> 4, t = tid & 15;
    float a = 0.0f;
    #pragma unroll 8
    for (int k = 0; k < XX; ++k) a += sx[s][k] * sx[t][k];
    G1[(b * TT + s) * TT + t] = a + 1.0f;
}

// ---------------------------------------------------------------------------
// Stage device functions. WG = (b, hc).
// ---------------------------------------------------------------------------
template <int OUT, bool RELU, bool GATE, bool PLUSONE, bool BIAS>
__device__ __forceinline__ void fwd_stage(
    const float* __restrict__ W, const float* __restrict__ bias,
    const float* __restrict__ hist, const float* __restrict__ Darr,
    const float* __restrict__ tg, float* __restrict__ outv,
    int b, int hc, int t, float lr,
    float* s_in, float* s_c, float* s_corr,
    int tid, int lane, int w)
{
    s_in[tid]       = hist[(b * TT + t) * HH + tid];
    s_in[tid + 256] = hist[(b * TT + t) * HH + tid + 256];
    __syncthreads();

    for (int s = w; s < t; s += 4) {
        const float4 h0 = *(const float4*)&hist[(b * TT + s) * HH + lane * 8];
        const float4 h1 = *(const float4*)&hist[(b * TT + s) * HH + lane * 8 + 4];
        float a = h0.x * s_in[lane * 8]     + h0.y * s_in[lane * 8 + 1] +
                  h0.z * s_in[lane * 8 + 2] + h0.w * s_in[lane * 8 + 3] +
                  h1.x * s_in[lane * 8 + 4] + h1.y * s_in[lane * 8 + 5] +
                  h1.z * s_in[lane * 8 + 6] + h1.w * s_in[lane * 8 + 7];
        a = wred(a);
        if (lane == 0) s_c[s] = a + (PLUSONE ? 1.0f : 0.0f);
    }
    __syncthreads();

    constexpr int RPW = OUT / 8;   // rows per WG: 64 (H) or 32 (Y)
    if (tid < RPW) {
        const int row = hc * RPW + tid;
        float cr = 0.0f;
        for (int s = 0; s < t; ++s) cr += Darr[(b * TT + s) * OUT + row] * s_c[s];
        s_corr[tid] = lr * cr;
    }
    __syncthreads();

    float xr[8];
    {
        const float4 a0 = *(const float4*)&s_in[lane * 8];
        const float4 a1 = *(const float4*)&s_in[lane * 8 + 4];
        xr[0] = a0.x; xr[1] = a0.y; xr[2] = a0.z; xr[3] = a0.w;
        xr[4] = a1.x; xr[5] = a1.y; xr[6] = a1.z; xr[7] = a1.w;
    }
    constexpr int RPL = RPW / 4;   // rows per wave: 16 or 8
    for (int r = 0; r < RPL; ++r) {
        const int row = hc * RPW + w * RPL + r;
        const float4 w0 = *(const float4*)&W[row * HH + lane * 8];
        const float4 w1 = *(const float4*)&W[row * HH + lane * 8 + 4];
        float a = w0.x * xr[0] + w0.y * xr[1] + w0.z * xr[2] + w0.w * xr[3] +
                  w1.x * xr[4] + w1.y * xr[5] + w1.z * xr[6] + w1.w * xr[7];
        a = wred(a);
        if (lane == 0) {
            float v = a - s_corr[w * RPL + r];
            if constexpr (BIAS) v += bias[row];
            if constexpr (RELU) v = fmaxf(v, 0.0f);
            if constexpr (GATE) v *= tg[(b * TT + t) * HH + row];
            stg(&outv[row], v);
        }
    }
}

__device__ __forceinline__ void bwd4_stage(
    const float* __restrict__ W4, const float* __restrict__ ty,
    const float* __restrict__ tg, const float* __restrict__ LOG,
    const float* __restrict__ HG, float* __restrict__ D4,
    float* __restrict__ D3,
    int b, int hc, int t, float lr,
    float* s_dlg, float* s_c, float (*s_part)[64],
    int tid, int lane, int w)
{
    s_dlg[tid] = (LOG[(b * TT + t) * YY + tid] - ty[(b * TT + t) * YY + tid]) * (2.0f / YY);
    __syncthreads();
    if (hc == 0) stg(&D4[(b * TT + t) * YY + tid], s_dlg[tid]);

    for (int s = w; s < t; s += 4) {
        const float4 d0 = *(const float4*)&D4[(b * TT + s) * YY + lane * 4];
        float a = d0.x * s_dlg[lane * 4]     + d0.y * s_dlg[lane * 4 + 1] +
                  d0.z * s_dlg[lane * 4 + 2] + d0.w * s_dlg[lane * 4 + 3];
        a = wred(a);
        if (lane == 0) s_c[s] = lr * a;
    }
    __syncthreads();

    const int h = hc * 64 + lane;
    float acc = 0.0f;
    for (int y = w * 64; y < w * 64 + 64; ++y) acc += W4[y * HH + h] * s_dlg[y];
    s_part[w][lane] = acc;
    __syncthreads();

    if (tid < 64) {
        const int hh = hc * 64 + tid;
        float sum = s_part[0][tid] + s_part[1][tid] + s_part[2][tid] + s_part[3][tid];
        for (int s = 0; s < t; ++s) sum -= HG[(b * TT + s) * HH + hh] * s_c[s];
        const float g = tg[(b * TT + t) * HH + hh];
        const float m = (HG[(b * TT + t) * HH + hh] > 0.0f) ? 1.0f : 0.0f;
        stg(&D3[(b * TT + t) * HH + hh], sum * g * m);
    }
}

template <bool EPI>
__device__ __forceinline__ void bwd_stage(
    const float* __restrict__ W, const float* __restrict__ Din,
    const float* __restrict__ hist, float* __restrict__ Dout,
    const float* __restrict__ Z1base, const float* __restrict__ G1,
    float* __restrict__ H1,
    int b, int hc, int t, float lr,
    float* s_v, float* s_c, float (*s_part)[64], float* s_g,
    int tid, int lane, int w)
{
    s_v[tid]       = Din[(b * TT + t) * HH + tid];
    s_v[tid + 256] = Din[(b * TT + t) * HH + tid + 256];
    __syncthreads();

    for (int s = w; s < t; s += 4) {
        const float4 d0 = *(const float4*)&Din[(b * TT + s) * HH + lane * 8];
        const float4 d1 = *(const float4*)&Din[(b * TT + s) * HH + lane * 8 + 4];
        float a = d0.x * s_v[lane * 8]     + d0.y * s_v[lane * 8 + 1] +
                  d0.z * s_v[lane * 8 + 2] + d0.w * s_v[lane * 8 + 3] +
                  d1.x * s_v[lane * 8 + 4] + d1.y * s_v[lane * 8 + 5] +
                  d1.z * s_v[lane * 8 + 6] + d1.w * s_v[lane * 8 + 7];
        a = wred(a);
        if (lane == 0) s_c[s] = lr * a;
    }
    if (EPI && tid < TT)
        s_g[tid] = G1[(b * TT + tid) * TT + ((t + 1 < TT) ? (t + 1) : 0)];
    __syncthreads();

    const int h = hc * 64 + lane;
    float acc = 0.0f;
    for (int i = w * 128; i < w * 128 + 128; ++i) acc += W[i * HH + h] * s_v[i];
    s_part[w][lane] = acc;
    __syncthreads();

    if (tid < 64) {
        const int hh = hc * 64 + tid;
        float sum = s_part[0][tid] + s_part[1][tid] + s_part[2][tid] + s_part[3][tid];
        for (int s = 0; s < t; ++s) sum -= hist[(b * TT + s) * HH + hh] * s_c[s];
        const float m = (hist[(b * TT + t) * HH + hh] > 0.0f) ? 1.0f : 0.0f;
        const float dz = sum * m;
        stg(&Dout[(b * TT + t) * HH + hh], dz);
        if (EPI && (t + 1 < TT)) {
            float cr = dz * s_g[t];
            for (int s = 0; s < t; ++s) cr += Dout[(b * TT + s) * HH + hh] * s_g[s];
            const float z = Z1base[(b * TT + t + 1) * HH + hh];
            stg(&H1[(b * TT + (t + 1)) * HH + hh], fmaxf(z - lr * cr, 0.0f));
        }
    }
}

// ---------------------------------------------------------------------------
// Persistent inner-loop kernel: T=16 steps x 6 stages, per-example flag
// barriers. grid: 128 WGs of 256. WG = (b, hc).
// ---------------------------------------------------------------------------
__global__ __launch_bounds__(256) void k_inner(
    const float* __restrict__ W2, const float* __restrict__ b2,
    const float* __restrict__ W3, const float* __restrict__ b3,
    const float* __restrict__ W4, const float* __restrict__ ty,
    const float* __restrict__ tg,
    const float* __restrict__ Z1base, const float* __restrict__ G1,
    float* __restrict__ H1, float* __restrict__ H2, float* __restrict__ HG,
    float* __restrict__ D1, float* __restrict__ D2, float* __restrict__ D3,
    float* __restrict__ D4, float* __restrict__ LOG,
    const float* __restrict__ loglr, unsigned* __restrict__ bar)
{
    const int wid = blockIdx.x;
    const int b = wid >> 3, hc = wid & 7;
    const int tid = threadIdx.x, lane = tid & 63, w = tid >> 6;
    const float lr = expf(loglr[0]);
    unsigned* myslots = bar + b * 128;   // 512B line per example, 8 slots 64B apart

    __shared__ float s_vec[HH];
    __shared__ float s_c[TT];
    __shared__ float s_corr[64];
    __shared__ float s_part[4][64];
    __shared__ float s_g[TT];

    unsigned bi = 0;
    for (int t = 0; t < TT; ++t) {
        // F2: h2 = relu(W2@h1 + b2 - lr*sum D2[s]*(h1_s.h1_t+1))
        fwd_stage<HH, true, false, true, true>(
            W2, b2, H1, D2, nullptr, H2 + (b * TT + t) * HH,
            b, hc, t, lr, s_vec, s_c, s_corr, tid, lane, w);
        gbar8(myslots, hc, ++bi);
        // F3: hg = relu(z3) * gate_t
        fwd_stage<HH, true, true, true, true>(
            W3, b3, H2, D3, tg, HG + (b * TT + t) * HH,
            b, hc, t, lr, s_vec, s_c, s_corr, tid, lane, w);
        gbar8(myslots, hc, ++bi);
        // F4: logit
        fwd_stage<YY, false, false, false, false>(
            W4, nullptr, HG, D4, nullptr, LOG + (b * TT + t) * YY,
            b, hc, t, lr, s_vec, s_c, s_corr, tid, lane, w);
        gbar8(myslots, hc, ++bi);
        // B4 -> D4[b][t], D3[b][t]
        bwd4_stage(W4, ty, tg, LOG, HG, D4, D3,
                   b, hc, t, lr, s_vec, s_c, s_part, tid, lane, w);
        gbar8(myslots, hc, ++bi);
        // B3 -> D2[b][t]
        bwd_stage<false>(W3, D3, H2, D2, nullptr, nullptr, nullptr,
                         b, hc, t, lr, s_vec, s_c, s_part, s_g, tid, lane, w);
        gbar8(myslots, hc, ++bi);
        // B2 -> D1[b][t] + h1_{t+1}
        bwd_stage<true>(W2, D2, H1, D1, Z1base, G1, H1,
                        b, hc, t, lr, s_vec, s_c, s_part, s_g, tid, lane, w);
        gbar8(myslots, hc, ++bi);
    }
}

// ---------------------------------------------------------------------------
// Phase-2 layer with FUSED ip computation:
// sip[s][l] = A[b][s] . (act[b][l] *? tg[b][l]) (+1)
// out[b][l][n] = post( W@actg + bias - lr*sum_s D[s][n]*sip[s][l] )
// ---------------------------------------------------------------------------
template <int K, int OUT, bool RELU, bool BIAS, bool GATEIN, bool PLUSONE>
__global__ __launch_bounds__(256) void k_layer(
    const float* __restrict__ W, const float* __restrict__ bias,
    const float* __restrict__ act, const float* __restrict__ tg,
    const float* __restrict__ A, const float* __restrict__ Dl,
    float* __restrict__ outp, const float* __restrict__ loglr)
{
    constexpr int NC = OUT / 64;
    constexpr int E = K / 64;
    const int blk = blockIdx.x;
    const int b = blk / (NC * 4);
    const int rem = blk % (NC * 4);
    const int nc = rem / 4, lc = rem % 4;
    const int base_n = nc * 64, base_l = lc * 32;
    const int tid = threadIdx.x;
    const int tn = tid & 31, tl = tid >> 5;
    const int lane = tid & 63, wv = tid >> 6;
    const float lr = expf(loglr[0]);

    __shared__ float lw[64][65];
    __shared__ float lx[32][65];
    __shared__ float sD[TT][64];
    __shared__ float sip[TT][33];

    #pragma unroll
    for (int rep = 0; rep < 4; ++rep) {
        const int flat = rep * 256 + tid;
        const int s = flat >> 6, n = flat & 63;
        sD[s][n] = Dl[(b * TT + s) * OUT + base_n + n];
    }

    // fused ip: wave wv handles s = wv, wv+4, wv+8, wv+12
    for (int s = wv; s < TT; s += 4) {
        float ar[E];
        #pragma unroll
        for (int j = 0; j < E; j += 4) {
            const float4 v = *(const float4*)&A[((long)b * TT + s) * K + lane * E + j];
            ar[j] = v.x; ar[j + 1] = v.y; ar[j + 2] = v.z; ar[j + 3] = v.w;
        }
        for (int l = 0; l < 32; ++l) {
            const float* ap = &act[((long)b * LL + base_l + l) * K + lane * E];
            float a = 0.0f;
            #pragma unroll
            for (int j = 0; j < E; j += 4) {
                const float4 v = *(const float4*)&ap[j];
                if constexpr (GATEIN) {
                    const float4 g = *(const float4*)
                        &tg[((long)b * LL + base_l + l) * K + lane * E + j];
                    a += v.x * g.x * ar[j]     + v.y * g.y * ar[j + 1] +
                         v.z * g.z * ar[j + 2] + v.w * g.w * ar[j + 3];
                } else {
                    a += v.x * ar[j]     + v.y * ar[j + 1] +
                         v.z * ar[j + 2] + v.w * ar[j + 3];
                }
            }
            a = wred(a);
            if (lane == 0) sip[s][l] = a + (PLUSONE ? 1.0f : 0.0f);
        }
    }

    float acc[2][4] = {};
    for (int kc = 0; kc < K; kc += 64) {
        __syncthreads();
        #pragma unroll
        for (int rep = 0; rep < 16; ++rep) {
            const int flat = rep * 256 + tid;
            const int i = flat >> 6, k = flat & 63;
            lw[i][k] = W[(base_n + i) * K + kc + k];
        }
        #pragma unroll
        for (int rep = 0; rep < 8; ++rep) {
            const int flat = rep * 256 + tid;
            const int l = flat >> 6, k = flat & 63;
            float v = act[((long)b * LL + base_l + l) * K + kc + k];
            if constexpr (GATEIN)
                v *= tg[((long)b * LL + base_l + l) * K + kc + k];
            lx[l][k] = v;
        }
        __syncthreads();
        #pragma unroll 4
        for (int k = 0; k < 64; ++k) {
            const float w0 = lw[tn][k], w1 = lw[tn + 32][k];
            const float x0 = lx[tl][k],      x1 = lx[tl + 8][k];
            const float x2 = lx[tl + 16][k], x3 = lx[tl + 24][k];
            acc[0][0] += w0 * x0; acc[0][1] += w0 * x1;
            acc[0][2] += w0 * x2; acc[0][3] += w0 * x3;
            acc[1][0] += w1 * x0; acc[1][1] += w1 * x1;
            acc[1][2] += w1 * x2; acc[1][3] += w1 * x3;
        }
    }

    #pragma unroll
    for (int i = 0; i < 2; ++i) {
        const int n = base_n + tn + i * 32;
        const float bv = BIAS ? bias[n] : 0.0f;
        #pragma unroll
        for (int j = 0; j < 4; ++j) {
            const int l = base_l + tl + j * 8;
            float corr = 0.0f;
            #pragma unroll
            for (int s = 0; s < TT; ++s)
                corr += sD[s][tn + i * 32] * sip[s][tl + j * 8];
            float v = acc[i][j] + bv - lr * corr;
            if constexpr (RELU) v = fmaxf(v, 0.0f);
            outp[((long)b * LL + l) * OUT + n] = v;
        }
    }
}

// ---------------------------------------------------------------------------
__global__ __launch_bounds__(64) void k_loss(
    const float* __restrict__ logit, const float* __restrict__ tey,
    float* __restrict__ loss, float* __restrict__ evalo)
{
    const int idx = blockIdx.x;
    const int lane = threadIdx.x;
    float a = 0.0f;
    #pragma unroll
    for (int j = 0; j < 4; ++j) {
        const float d = logit[(long)idx * YY + lane * 4 + j] -
                        tey[(long)idx * YY + lane * 4 + j];
        a += d * d;
    }
    a = wred(a);
    if (lane == 0) {
        const float v = a * (1.0f / YY);
        loss[idx] = v;
        evalo[idx] = v;
    }
}

// ---------------------------------------------------------------------------
extern "C" void kernel_launch(void* const* d_in, const int* in_sizes, int n_in,
                              void* d_out, int out_size, void* d_ws, size_t ws_size,
                              hipStream_t stream)
{
    const float* tx    = (const float*)d_in[0];
    const float* ty    = (const float*)d_in[1];
    const float* tex   = (const float*)d_in[2];
    const float* tey   = (const float*)d_in[3];
    const float* tg    = (const float*)d_in[4];
    const float* teg   = (const float*)d_in[5];
    const float* W1    = (const float*)d_in[6];
    const float* b1    = (const float*)d_in[7];
    const float* W2    = (const float*)d_in[8];
    const float* b2    = (const float*)d_in[9];
    const float* W3    = (const float*)d_in[10];
    const float* b3    = (const float*)d_in[11];
    const float* W4    = (const float*)d_in[12];
    const float* loglr = (const float*)d_in[13];

    float* out = (float*)d_out;
    float* ws  = (float*)d_ws;

    // workspace layout (floats)
    float* Z1base = ws;                 // 131072
    float* G1     = ws + 131072;        // 4096
    float* H1     = ws + 135168;        // 131072
    float* H2     = ws + 266240;        // 131072
    float* HG     = ws + 397312;        // 131072
    float* D1     = ws + 528384;        // 131072
    float* D2     = ws + 659456;        // 131072
    float* D3     = ws + 790528;        // 131072
    float* D4     = ws + 921600;        // 65536
    float* LOG    = ws + 987136;        // 65536 (per (b,t) now)
    unsigned* bar = (unsigned*)(ws + 1052672);  // 16 x 128 dwords (8KB)
    float* ActA   = ws + 1054720;       // 1048576
    float* ActB   = ws + 2103296;       // 1048576

    hipMemsetAsync(bar, 0, TB * 128 * sizeof(unsigned), stream);

    k_z1<<<64, 256, 0, stream>>>(W1, b1, tx, Z1base, H1);
    k_gram<<<TB, 256, 0, stream>>>(tx, loglr, G1, out);

    k_inner<<<128, 256, 0, stream>>>(W2, b2, W3, b3, W4, ty, tg,
                                     Z1base, G1, H1, H2, HG,
                                     D1, D2, D3, D4, LOG, loglr, bar);

    // ---- Phase 2: test-set forward with final (rank-16-corrected) weights ----
    k_layer<XX, HH, true, true, false, true><<<TB * 8 * 4, 256, 0, stream>>>(
        W1, b1, tex, nullptr, tx, D1, ActA, loglr);
    k_layer<HH, HH, true, true, false, true><<<TB * 8 * 4, 256, 0, stream>>>(
        W2, b2, ActA, nullptr, H1, D2, ActB, loglr);
    k_layer<HH, HH, true, true, false, true><<<TB * 8 * 4, 256, 0, stream>>>(
        W3, b3, ActB, nullptr, H2, D3, ActA, loglr);
    k_layer<HH, YY, false, false, true, false><<<TB * 4 * 4, 256, 0, stream>>>(
        W4, nullptr, ActA, teg, HG, D4, out + 4097, loglr);

    k_loss<<<TB * LL, 64, 0, stream>>>(out + 4097, tey, out, out + 2049);
}

// Round 5
// 1093.282 us; speedup vs baseline: 1.7928x; 1.2742x over previous
//
#include <hip/hip_runtime.h>
#include <math.h>

// Problem dims
#define TB 16   // batch (tasks)
#define TT 16   // train steps
#define LL 128  // test length
#define XX 256  // x dim
#define HH 512  // hidden
#define YY 256  // y dim

__device__ __forceinline__ float wred(float v) {
    v += __shfl_xor(v, 32);
    v += __shfl_xor(v, 16);
    v += __shfl_xor(v, 8);
    v += __shfl_xor(v, 4);
    v += __shfl_xor(v, 2);
    v += __shfl_xor(v, 1);
    return v;
}

// Coherent (agent-scope, through-to-MALL) store for cross-WG data.
__device__ __forceinline__ void stg(float* p, float v) {
    __hip_atomic_store(p, v, __ATOMIC_RELAXED, __HIP_MEMORY_SCOPE_AGENT);
}

// Fence-free per-example barrier (8 WGs, private 512B line, 8 flag slots).
__device__ __forceinline__ void gbar8(unsigned* slots, int hc, unsigned target) {
    __syncthreads();   // prior stores vmcnt-drained here
    if (threadIdx.x < 8) {
        if (threadIdx.x == hc)
            __hip_atomic_store(&slots[hc * 16], target, __ATOMIC_RELAXED,
                               __HIP_MEMORY_SCOPE_AGENT);
        while (__hip_atomic_load(&slots[threadIdx.x * 16], __ATOMIC_RELAXED,
                                 __HIP_MEMORY_SCOPE_AGENT) < target)
            __builtin_amdgcn_s_sleep(1);
    }
    __atomic_signal_fence(__ATOMIC_ACQ_REL);
    __syncthreads();
}

// ---------------------------------------------------------------------------
// Z1 = train_x @ W1^T + b1 tiled GEMM; epilogue H1[b][0] = relu(Z1[b][0]).
// ---------------------------------------------------------------------------
__global__ __launch_bounds__(256) void k_z1(
    const float* __restrict__ W1, const float* __restrict__ b1,
    const float* __restrict__ tx, float* __restrict__ Z1base,
    float* __restrict__ H1)
{
    const int nc = blockIdx.x & 7, mc = blockIdx.x >> 3;
    const int tid = threadIdx.x;
    const int tn = tid & 31, tl = tid >> 5;
    __shared__ float lw[64][65];
    __shared__ float lx[32][65];
    float acc[2][4] = {};
    for (int kc = 0; kc < XX; kc += 64) {
        __syncthreads();
        #pragma unroll
        for (int rep = 0; rep < 4; ++rep) {
            const int idx4 = (rep * 256 + tid) * 4;
            const int i = idx4 >> 6, k = idx4 & 63;
            const float4 v = *(const float4*)&W1[(nc * 64 + i) * XX + kc + k];
            lw[i][k] = v.x; lw[i][k + 1] = v.y; lw[i][k + 2] = v.z; lw[i][k + 3] = v.w;
        }
        #pragma unroll
        for (int rep = 0; rep < 2; ++rep) {
            const int idx4 = (rep * 256 + tid) * 4;
            const int l = idx4 >> 6, k = idx4 & 63;
            const float4 v = *(const float4*)&tx[(mc * 32 + l) * XX + kc + k];
            lx[l][k] = v.x; lx[l][k + 1] = v.y; lx[l][k + 2] = v.z; lx[l][k + 3] = v.w;
        }
        __syncthreads();
        #pragma unroll 4
        for (int k = 0; k < 64; ++k) {
            const float w0 = lw[tn][k], w1 = lw[tn + 32][k];
            const float x0 = lx[tl][k],      x1 = lx[tl + 8][k];
            const float x2 = lx[tl + 16][k], x3 = lx[tl + 24][k];
            acc[0][0] += w0 * x0; acc[0][1] += w0 * x1;
            acc[0][2] += w0 * x2; acc[0][3] += w0 * x3;
            acc[1][0] += w1 * x0; acc[1][1] += w1 * x1;
            acc[1][2] += w1 * x2; acc[1][3] += w1 * x3;
        }
    }
    #pragma unroll
    for (int i = 0; i < 2; ++i) {
        const int n = nc * 64 + tn + i * 32;
        const float bv = b1[n];
        #pragma unroll
        for (int j = 0; j < 4; ++j) {
            const int m = mc * 32 + tl + j * 8;
            const float v = acc[i][j] + bv;
            Z1base[m * HH + n] = v;
            if ((m & 15) == 0) H1[m * HH + n] = fmaxf(v, 0.0f);  // t==0
        }
    }
}

// ---------------------------------------------------------------------------
// Gram: G1[b][s][t] = x_s.x_t + 1 ; also out[2048] = exp(loglr).
// ---------------------------------------------------------------------------
__global__ __launch_bounds__(256) void k_gram(
    const float* __restrict__ tx, const float* __restrict__ loglr,
    float* __restrict__ G1, float* __restrict__ out)
{
    const int b = blockIdx.x;
    const int tid = threadIdx.x;
    __shared__ float sx[TT][XX + 1];
    #pragma unroll
    for (int rep = 0; rep < 16; ++rep) {
        const int flat = rep * 256 + tid;
        const int s = flat >> 8, k = flat & 255;
        sx[s][k] = tx[(b * TT + s) * XX + k];
    }
    __syncthreads();
    if (b == 0 && tid == 0) out[2048] = expf(loglr[0]);
    const int s = tid >> 4, t = tid & 15;
    float a = 0.0f;
    #pragma unroll 8
    for (int k = 0; k < XX; ++k) a += sx[s][k] * sx[t][k];
    G1[(b * TT + s) * TT + t] = a + 1.0f;
}

// ---------------------------------------------------------------------------
// Inner-loop stage device functions. WG = (b, hc). No wred anywhere.
// ---------------------------------------------------------------------------
template <int OUT, bool RELU, bool GATE, bool PLUSONE, bool BIAS>
__device__ __forceinline__ void fwd_stage(
    const float* __restrict__ W, const float* __restrict__ bias,
    const float* __restrict__ hist, const float* __restrict__ Darr,
    const float* __restrict__ tg, float* __restrict__ outv,
    int b, int hc, int t, float lr,
    float* s_in, float* s_c, float (*s_cp)[17], float* s_red, float* lwT,
    int tid)
{
    constexpr int RPW = OUT / 8;     // rows per WG: 64 or 32
    constexpr int KQ  = 256 / RPW;   // k-split: 4 or 8
    constexpr int KL  = 128 / KQ;    // per-thread k per 128-tile: 32 or 16
    constexpr int STR = RPW + 1;     // lwT stride

    s_in[tid]       = hist[(b * TT + t) * HH + tid];
    s_in[tid + 256] = hist[(b * TT + t) * HH + tid + 256];
    __syncthreads();

    // coefficient partials: c[s] = hist_s . x_t (+1); thread (s, ch) does 32 elems
    {
        const int s = tid >> 4, ch = tid & 15;
        if (s < t) {
            const float* hp = &hist[(b * TT + s) * HH + ch * 32];
            const float* xp = &s_in[ch * 32];
            float p = 0.f;
            #pragma unroll
            for (int j = 0; j < 32; j += 4) {
                const float4 h4 = *(const float4*)&hp[j];
                p += h4.x * xp[j] + h4.y * xp[j + 1] + h4.z * xp[j + 2] + h4.w * xp[j + 3];
            }
            s_cp[s][ch] = p;
        }
    }
    __syncthreads();
    if (tid < 16 && tid < t) {
        float c = 0.f;
        #pragma unroll
        for (int ch = 0; ch < 16; ++ch) c += s_cp[tid][ch];
        s_c[tid] = c + (PLUSONE ? 1.0f : 0.0f);
    }

    // main matvec: LDS-transposed W tiles, thread-per-row, KQ-way k split
    const int rloc = tid % RPW, kq = tid / RPW;
    float acc = 0.f;
    for (int kc = 0; kc < HH; kc += 128) {
        __syncthreads();
        constexpr int REPS = (RPW * 128) / 1024;   // float4 reps: 8 or 4
        #pragma unroll
        for (int rep = 0; rep < REPS; ++rep) {
            const int idx4 = (rep * 256 + tid) * 4;
            const int i = idx4 >> 7, k = idx4 & 127;
            const float4 wv = *(const float4*)&W[(long)(hc * RPW + i) * HH + kc + k];
            lwT[(k + 0) * STR + i] = wv.x;
            lwT[(k + 1) * STR + i] = wv.y;
            lwT[(k + 2) * STR + i] = wv.z;
            lwT[(k + 3) * STR + i] = wv.w;
        }
        __syncthreads();
        const float* xp = &s_in[kc + kq * KL];
        const float* wp = &lwT[(kq * KL) * STR + rloc];
        #pragma unroll
        for (int k = 0; k < KL; ++k) acc += wp[k * STR] * xp[k];
    }
    s_red[tid] = acc;   // [kq][rloc] flat == tid
    __syncthreads();

    if (tid < RPW) {
        const int row = hc * RPW + tid;
        float z = 0.f;
        #pragma unroll
        for (int q = 0; q < KQ; ++q) z += s_red[q * RPW + tid];
        float cr = 0.f;
        for (int s = 0; s < t; ++s) cr += Darr[(b * TT + s) * OUT + row] * s_c[s];
        z -= lr * cr;
        if constexpr (BIAS) z += bias[row];
        if constexpr (RELU) z = fmaxf(z, 0.0f);
        if constexpr (GATE) z *= tg[(b * TT + t) * HH + row];
        stg(&outv[row], z);
    }
}

__device__ __forceinline__ void bwd4_stage(
    const float* __restrict__ W4, const float* __restrict__ ty,
    const float* __restrict__ tg, const float* __restrict__ LOG,
    const float* __restrict__ HG, float* __restrict__ D4,
    float* __restrict__ D3,
    int b, int hc, int t, float lr,
    float* s_dlg, float* s_c, float (*s_cp)[17], float* s_red,
    int tid, int lane, int w)
{
    s_dlg[tid] = (LOG[(b * TT + t) * YY + tid] - ty[(b * TT + t) * YY + tid]) * (2.0f / YY);
    __syncthreads();
    if (hc == 0) stg(&D4[(b * TT + t) * YY + tid], s_dlg[tid]);

    {   // bc[s] = lr * (D4_s . dlg); thread (s, ch) does 16 elems
        const int s = tid >> 4, ch = tid & 15;
        if (s < t) {
            const float* dp = &D4[(b * TT + s) * YY + ch * 16];
            const float* xp = &s_dlg[ch * 16];
            float p = 0.f;
            #pragma unroll
            for (int j = 0; j < 16; j += 4) {
                const float4 d4 = *(const float4*)&dp[j];
                p += d4.x * xp[j] + d4.y * xp[j + 1] + d4.z * xp[j + 2] + d4.w * xp[j + 3];
            }
            s_cp[s][ch] = p;
        }
    }
    __syncthreads();
    if (tid < 16 && tid < t) {
        float c = 0.f;
        #pragma unroll
        for (int ch = 0; ch < 16; ++ch) c += s_cp[tid][ch];
        s_c[tid] = lr * c;
    }

    const int h = hc * 64 + lane;
    float acc = 0.f;
    for (int y = w * 64; y < w * 64 + 64; ++y) acc += W4[(long)y * HH + h] * s_dlg[y];
    s_red[w * 64 + lane] = acc;
    __syncthreads();

    if (tid < 64) {
        const int hh = hc * 64 + tid;
        float sum = s_red[tid] + s_red[64 + tid] + s_red[128 + tid] + s_red[192 + tid];
        for (int s = 0; s < t; ++s) sum -= HG[(b * TT + s) * HH + hh] * s_c[s];
        const float g = tg[(b * TT + t) * HH + hh];
        const float m = (HG[(b * TT + t) * HH + hh] > 0.0f) ? 1.0f : 0.0f;
        stg(&D3[(b * TT + t) * HH + hh], sum * g * m);
    }
}

template <bool EPI>
__device__ __forceinline__ void bwd_stage(
    const float* __restrict__ W, const float* __restrict__ Din,
    const float* __restrict__ hist, float* __restrict__ Dout,
    const float* __restrict__ Z1base, const float* __restrict__ G1,
    float* __restrict__ H1,
    int b, int hc, int t, float lr,
    float* s_v, float* s_c, float (*s_cp)[17], float* s_red, float* s_g,
    int tid, int lane, int w)
{
    s_v[tid]       = Din[(b * TT + t) * HH + tid];
    s_v[tid + 256] = Din[(b * TT + t) * HH + tid + 256];
    if (EPI && tid < TT)
        s_g[tid] = G1[(b * TT + tid) * TT + ((t + 1 < TT) ? (t + 1) : 0)];
    __syncthreads();

    {   // bc[s] = lr * (Din_s . dz_t); thread (s, ch) does 32 elems
        const int s = tid >> 4, ch = tid & 15;
        if (s < t) {
            const float* dp = &Din[(b * TT + s) * HH + ch * 32];
            const float* xp = &s_v[ch * 32];
            float p = 0.f;
            #pragma unroll
            for (int j = 0; j < 32; j += 4) {
                const float4 d4 = *(const float4*)&dp[j];
                p += d4.x * xp[j] + d4.y * xp[j + 1] + d4.z * xp[j + 2] + d4.w * xp[j + 3];
            }
            s_cp[s][ch] = p;
        }
    }
    __syncthreads();
    if (tid < 16 && tid < t) {
        float c = 0.f;
        #pragma unroll
        for (int ch = 0; ch < 16; ++ch) c += s_cp[tid][ch];
        s_c[tid] = lr * c;
    }

    const int h = hc * 64 + lane;
    float acc = 0.f;
    for (int i = w * 128; i < w * 128 + 128; ++i) acc += W[(long)i * HH + h] * s_v[i];
    s_red[w * 64 + lane] = acc;
    __syncthreads();

    if (tid < 64) {
        const int hh = hc * 64 + tid;
        float sum = s_red[tid] + s_red[64 + tid] + s_red[128 + tid] + s_red[192 + tid];
        for (int s = 0; s < t; ++s) sum -= hist[(b * TT + s) * HH + hh] * s_c[s];
        const float m = (hist[(b * TT + t) * HH + hh] > 0.0f) ? 1.0f : 0.0f;
        const float dz = sum * m;
        stg(&Dout[(b * TT + t) * HH + hh], dz);
        if (EPI && (t + 1 < TT)) {
            float cr = dz * s_g[t];
            for (int s = 0; s < t; ++s) cr += Dout[(b * TT + s) * HH + hh] * s_g[s];
            const float z = Z1base[(b * TT + t + 1) * HH + hh];
            stg(&H1[(b * TT + (t + 1)) * HH + hh], fmaxf(z - lr * cr, 0.0f));
        }
    }
}

// ---------------------------------------------------------------------------
// Persistent inner loop: 16 steps x 6 stages, per-example flag barriers.
// grid: 128 WGs of 256. wid = hc*16 + b (keeps an example's 8 WGs on one XCD).
// ---------------------------------------------------------------------------
__global__ __launch_bounds__(256) void k_inner(
    const float* __restrict__ W2, const float* __restrict__ b2,
    const float* __restrict__ W3, const float* __restrict__ b3,
    const float* __restrict__ W4, const float* __restrict__ ty,
    const float* __restrict__ tg,
    const float* __restrict__ Z1base, const float* __restrict__ G1,
    float* __restrict__ H1, float* __restrict__ H2, float* __restrict__ HG,
    float* __restrict__ D1, float* __restrict__ D2, float* __restrict__ D3,
    float* __restrict__ D4, float* __restrict__ LOG,
    const float* __restrict__ loglr, unsigned* __restrict__ bar)
{
    const int wid = blockIdx.x;
    const int b = wid & 15, hc = wid >> 4;
    const int tid = threadIdx.x, lane = tid & 63, w = tid >> 6;
    const float lr = expf(loglr[0]);
    unsigned* myslots = bar + b * 128;

    __shared__ float s_in[HH];
    __shared__ float s_c[TT];
    __shared__ float s_cp[TT][17];
    __shared__ float s_red[256];
    __shared__ float s_g[TT];
    __shared__ float lwT[128 * 65];

    unsigned bi = 0;
    for (int t = 0; t < TT; ++t) {
        fwd_stage<HH, true, false, true, true>(
            W2, b2, H1, D2, nullptr, H2 + (b * TT + t) * HH,
            b, hc, t, lr, s_in, s_c, s_cp, s_red, lwT, tid);
        gbar8(myslots, hc, ++bi);
        fwd_stage<HH, true, true, true, true>(
            W3, b3, H2, D3, tg, HG + (b * TT + t) * HH,
            b, hc, t, lr, s_in, s_c, s_cp, s_red, lwT, tid);
        gbar8(myslots, hc, ++bi);
        fwd_stage<YY, false, false, false, false>(
            W4, nullptr, HG, D4, nullptr, LOG + (b * TT + t) * YY,
            b, hc, t, lr, s_in, s_c, s_cp, s_red, lwT, tid);
        gbar8(myslots, hc, ++bi);
        bwd4_stage(W4, ty, tg, LOG, HG, D4, D3,
                   b, hc, t, lr, s_in, s_c, s_cp, s_red, tid, lane, w);
        gbar8(myslots, hc, ++bi);
        bwd_stage<false>(W3, D3, H2, D2, nullptr, nullptr, nullptr,
                         b, hc, t, lr, s_in, s_c, s_cp, s_red, s_g, tid, lane, w);
        gbar8(myslots, hc, ++bi);
        bwd_stage<true>(W2, D2, H1, D1, Z1base, G1, H1,
                        b, hc, t, lr, s_in, s_c, s_cp, s_red, s_g, tid, lane, w);
        gbar8(myslots, hc, ++bi);
    }
}

// ---------------------------------------------------------------------------
// Phase-2 ip (GEMM-style, no wred): ip[b][s][l] = A[b][s].(act[b][l]*?tg) (+1)
// grid: B*8 WGs of 256; WG = (b, 16-l chunk); thread = (s, j).
// ---------------------------------------------------------------------------
template <int K, bool PLUSONE, bool GATE>
__global__ __launch_bounds__(256) void k_ip(
    const float* __restrict__ A, const float* __restrict__ act,
    const float* __restrict__ tg, float* __restrict__ ip)
{
    const int b = blockIdx.x >> 3, lc = blockIdx.x & 7;
    const int tid = threadIdx.x;
    const int s = tid >> 4, j = tid & 15;
    __shared__ float sA[TT][68];
    __shared__ float sX[TT][68];
    float acc = 0.f;
    for (int kc = 0; kc < K; kc += 64) {
        __syncthreads();
        {
            const int idx4 = tid * 4;
            const int r = idx4 >> 6, k = idx4 & 63;
            const float4 va = *(const float4*)&A[((long)b * TT + r) * K + kc + k];
            sA[r][k] = va.x; sA[r][k + 1] = va.y; sA[r][k + 2] = va.z; sA[r][k + 3] = va.w;
            float4 vx = *(const float4*)&act[((long)b * LL + lc * 16 + r) * K + kc + k];
            if constexpr (GATE) {
                const float4 g = *(const float4*)&tg[((long)b * LL + lc * 16 + r) * K + kc + k];
                vx.x *= g.x; vx.y *= g.y; vx.z *= g.z; vx.w *= g.w;
            }
            sX[r][k] = vx.x; sX[r][k + 1] = vx.y; sX[r][k + 2] = vx.z; sX[r][k + 3] = vx.w;
        }
        __syncthreads();
        #pragma unroll 8
        for (int k = 0; k < 64; ++k) acc += sA[s][k] * sX[j][k];
    }
    ip[((long)b * TT + s) * LL + lc * 16 + j] = acc + (PLUSONE ? 1.0f : 0.0f);
}

// ---------------------------------------------------------------------------
// Phase-2 layer: out[b][l][n] = post( W@actg + bias - lr*sum_s D[s][n]*ip[s][l] )
// ---------------------------------------------------------------------------
template <int K, int OUT, bool RELU, bool BIAS, bool GATEIN>
__global__ __launch_bounds__(256) void k_layer(
    const float* __restrict__ W, const float* __restrict__ bias,
    const float* __restrict__ act, const float* __restrict__ tg,
    const float* __restrict__ IPa, const float* __restrict__ Dl,
    float* __restrict__ outp, const float* __restrict__ loglr)
{
    constexpr int NC = OUT / 64;
    const int blk = blockIdx.x;
    const int b = blk / (NC * 4);
    const int rem = blk % (NC * 4);
    const int nc = rem / 4, lc = rem % 4;
    const int base_n = nc * 64, base_l = lc * 32;
    const int tid = threadIdx.x;
    const int tn = tid & 31, tl = tid >> 5;
    const float lr = expf(loglr[0]);

    __shared__ float lw[64][65];
    __shared__ float lx[32][65];
    __shared__ float sD[TT][64];
    __shared__ float sip[TT][33];

    #pragma unroll
    for (int rep = 0; rep < 4; ++rep) {
        const int flat = rep * 256 + tid;
        const int s = flat >> 6, n = flat & 63;
        sD[s][n] = Dl[(b * TT + s) * OUT + base_n + n];
    }
    #pragma unroll
    for (int rep = 0; rep < 2; ++rep) {
        const int flat = rep * 256 + tid;
        const int s = flat >> 5, l = flat & 31;
        sip[s][l] = IPa[((long)b * TT + s) * LL + base_l + l];
    }

    float acc[2][4] = {};
    for (int kc = 0; kc < K; kc += 64) {
        __syncthreads();
        #pragma unroll
        for (int rep = 0; rep < 4; ++rep) {
            const int idx4 = (rep * 256 + tid) * 4;
            const int i = idx4 >> 6, k = idx4 & 63;
            const float4 v = *(const float4*)&W[(long)(base_n + i) * K + kc + k];
            lw[i][k] = v.x; lw[i][k + 1] = v.y; lw[i][k + 2] = v.z; lw[i][k + 3] = v.w;
        }
        #pragma unroll
        for (int rep = 0; rep < 2; ++rep) {
            const int idx4 = (rep * 256 + tid) * 4;
            const int l = idx4 >> 6, k = idx4 & 63;
            float4 v = *(const float4*)&act[((long)b * LL + base_l + l) * K + kc + k];
            if constexpr (GATEIN) {
                const float4 g = *(const float4*)&tg[((long)b * LL + base_l + l) * K + kc + k];
                v.x *= g.x; v.y *= g.y; v.z *= g.z; v.w *= g.w;
            }
            lx[l][k] = v.x; lx[l][k + 1] = v.y; lx[l][k + 2] = v.z; lx[l][k + 3] = v.w;
        }
        __syncthreads();
        #pragma unroll 4
        for (int k = 0; k < 64; ++k) {
            const float w0 = lw[tn][k], w1 = lw[tn + 32][k];
            const float x0 = lx[tl][k],      x1 = lx[tl + 8][k];
            const float x2 = lx[tl + 16][k], x3 = lx[tl + 24][k];
            acc[0][0] += w0 * x0; acc[0][1] += w0 * x1;
            acc[0][2] += w0 * x2; acc[0][3] += w0 * x3;
            acc[1][0] += w1 * x0; acc[1][1] += w1 * x1;
            acc[1][2] += w1 * x2; acc[1][3] += w1 * x3;
        }
    }

    #pragma unroll
    for (int i = 0; i < 2; ++i) {
        const int n = base_n + tn + i * 32;
        const float bv = BIAS ? bias[n] : 0.0f;
        #pragma unroll
        for (int j = 0; j < 4; ++j) {
            const int l = base_l + tl + j * 8;
            float corr = 0.0f;
            #pragma unroll
            for (int s = 0; s < TT; ++s)
                corr += sD[s][tn + i * 32] * sip[s][tl + j * 8];
            float v = acc[i][j] + bv - lr * corr;
            if constexpr (RELU) v = fmaxf(v, 0.0f);
            outp[((long)b * LL + l) * OUT + n] = v;
        }
    }
}

// ---------------------------------------------------------------------------
__global__ __launch_bounds__(64) void k_loss(
    const float* __restrict__ logit, const float* __restrict__ tey,
    float* __restrict__ loss, float* __restrict__ evalo)
{
    const int idx = blockIdx.x;
    const int lane = threadIdx.x;
    float a = 0.0f;
    #pragma unroll
    for (int j = 0; j < 4; ++j) {
        const float d = logit[(long)idx * YY + lane * 4 + j] -
                        tey[(long)idx * YY + lane * 4 + j];
        a += d * d;
    }
    a = wred(a);
    if (lane == 0) {
        const float v = a * (1.0f / YY);
        loss[idx] = v;
        evalo[idx] = v;
    }
}

// ---------------------------------------------------------------------------
extern "C" void kernel_launch(void* const* d_in, const int* in_sizes, int n_in,
                              void* d_out, int out_size, void* d_ws, size_t ws_size,
                              hipStream_t stream)
{
    const float* tx    = (const float*)d_in[0];
    const float* ty    = (const float*)d_in[1];
    const float* tex   = (const float*)d_in[2];
    const float* tey   = (const float*)d_in[3];
    const float* tg    = (const float*)d_in[4];
    const float* teg   = (const float*)d_in[5];
    const float* W1    = (const float*)d_in[6];
    const float* b1    = (const float*)d_in[7];
    const float* W2    = (const float*)d_in[8];
    const float* b2    = (const float*)d_in[9];
    const float* W3    = (const float*)d_in[10];
    const float* b3    = (const float*)d_in[11];
    const float* W4    = (const float*)d_in[12];
    const float* loglr = (const float*)d_in[13];

    float* out = (float*)d_out;
    float* ws  = (float*)d_ws;

    // workspace layout (floats)
    float* Z1base = ws;                 // 131072
    float* G1     = ws + 131072;        // 4096
    float* H1     = ws + 135168;        // 131072
    float* H2     = ws + 266240;        // 131072
    float* HG     = ws + 397312;        // 131072
    float* D1     = ws + 528384;        // 131072
    float* D2     = ws + 659456;        // 131072
    float* D3     = ws + 790528;        // 131072
    float* D4     = ws + 921600;        // 65536
    float* LOG    = ws + 987136;        // 65536
    float* IP     = ws + 1052672;       // 32768
    unsigned* bar = (unsigned*)(ws + 1085440);  // 2048 dwords
    float* ActA   = ws + 1087488;       // 1048576
    float* ActB   = ws + 2136064;       // 1048576

    hipMemsetAsync(bar, 0, TB * 128 * sizeof(unsigned), stream);

    k_z1<<<64, 256, 0, stream>>>(W1, b1, tx, Z1base, H1);
    k_gram<<<TB, 256, 0, stream>>>(tx, loglr, G1, out);

    k_inner<<<128, 256, 0, stream>>>(W2, b2, W3, b3, W4, ty, tg,
                                     Z1base, G1, H1, H2, HG,
                                     D1, D2, D3, D4, LOG, loglr, bar);

    // ---- Phase 2: test-set forward with final (rank-16-corrected) weights ----
    k_ip<XX, true, false><<<TB * 8, 256, 0, stream>>>(tx, tex, nullptr, IP);
    k_layer<XX, HH, true, true, false><<<TB * 8 * 4, 256, 0, stream>>>(
        W1, b1, tex, nullptr, IP, D1, ActA, loglr);

    k_ip<HH, true, false><<<TB * 8, 256, 0, stream>>>(H1, ActA, nullptr, IP);
    k_layer<HH, HH, true, true, false><<<TB * 8 * 4, 256, 0, stream>>>(
        W2, b2, ActA, nullptr, IP, D2, ActB, loglr);

    k_ip<HH, true, false><<<TB * 8, 256, 0, stream>>>(H2, ActB, nullptr, IP);
    k_layer<HH, HH, true, true, false><<<TB * 8 * 4, 256, 0, stream>>>(
        W3, b3, ActB, nullptr, IP, D3, ActA, loglr);

    k_ip<HH, false, true><<<TB * 8, 256, 0, stream>>>(HG, ActA, teg, IP);
    k_layer<HH, YY, false, false, true><<<TB * 4 * 4, 256, 0, stream>>>(
        W4, nullptr, ActA, teg, IP, D4, out + 4097, loglr);

    k_loss<<<TB * LL, 64, 0, stream>>>(out + 4097, tey, out, out + 2049);
}